// Round 9
// baseline (255.658 us; speedup 1.0000x reference)
//
#include <hip/hip_runtime.h>
#include <stdint.h>

typedef __attribute__((ext_vector_type(8))) short short8;
typedef __attribute__((ext_vector_type(4))) float f32x4;

static __device__ __forceinline__ ushort f2bf(float f) {
  uint32_t u = __float_as_uint(f);
  uint32_t r = (u + 0x7FFFu + ((u >> 16) & 1u)) >> 16;
  return (ushort)r;
}
static __device__ __forceinline__ float bf2f(ushort h) {
  return __uint_as_float(((uint32_t)h) << 16);
}

// ---------------------------------------------------------------------------
// KNN top-3, f64-exact selection, branchless insert. 4 threads/point.
// ---------------------------------------------------------------------------
static __device__ __forceinline__ void ins3b(double d, int i,
    double& b0, double& b1, double& b2, int& i0, int& i1, int& i2) {
  const bool c0 = d < b0, c1 = d < b1, c2 = d < b2;
  const double nb0 = c0 ? d : b0;
  const int    ni0 = c0 ? i : i0;
  const double nb1 = c0 ? b0 : (c1 ? d : b1);
  const int    ni1 = c0 ? i0 : (c1 ? i : i1);
  const double nb2 = c1 ? b1 : (c2 ? d : b2);
  const int    ni2 = c1 ? i1 : (c2 ? i : i2);
  b0 = nb0; b1 = nb1; b2 = nb2; i0 = ni0; i1 = ni1; i2 = ni2;
}

__global__ __launch_bounds__(256) void knn_kernel(
    const float* __restrict__ pos, const float* __restrict__ pos_skip,
    int4* __restrict__ idx_out, float4* __restrict__ w_out)
{
  __shared__ float pc[3072];
  const int b   = blockIdx.x >> 6;      // 64 blocks per batch
  const int blk = blockIdx.x & 63;      // 64 fine points per block
  for (int j = threadIdx.x; j < 3072; j += 256) pc[j] = pos[b * 3072 + j];
  __syncthreads();

  const int p   = threadIdx.x >> 2;     // point within block (0..63)
  const int sub = threadIdx.x & 3;      // candidate slice   (0..3)
  const int row = b * 4096 + blk * 64 + p;
  const double px = (double)pos_skip[(size_t)row * 3 + 0];
  const double py = (double)pos_skip[(size_t)row * 3 + 1];
  const double pz = (double)pos_skip[(size_t)row * 3 + 2];

  double b0 = 1e300, b1 = 1e300, b2 = 1e300;
  int i0 = 0, i1 = 0, i2 = 0;
#pragma unroll 4
  for (int j = 0; j < 256; ++j) {
    const int i = j * 4 + sub;
    const double dx = (double)pc[i * 3 + 0] - px;
    const double dy = (double)pc[i * 3 + 1] - py;
    const double dz = (double)pc[i * 3 + 2] - pz;
    const double d = dx * dx + dy * dy + dz * dz;
    ins3b(d, i, b0, b1, b2, i0, i1, i2);
  }
#pragma unroll
  for (int m = 1; m <= 2; m <<= 1) {
    const double c0 = __shfl_xor(b0, m), c1 = __shfl_xor(b1, m), c2 = __shfl_xor(b2, m);
    const int    j0 = __shfl_xor(i0, m), j1 = __shfl_xor(i1, m), j2 = __shfl_xor(i2, m);
    ins3b(c0, j0, b0, b1, b2, i0, i1, i2);
    ins3b(c1, j1, b0, b1, b2, i0, i1, i2);
    ins3b(c2, j2, b0, b1, b2, i0, i1, i2);
  }
  if (sub == 0) {
    const double w0 = 1.0 / (sqrt(b0) + 1e-8);
    const double w1 = 1.0 / (sqrt(b1) + 1e-8);
    const double w2 = 1.0 / (sqrt(b2) + 1e-8);
    const double den = w0 + w1 + w2 + 1e-8;
    idx_out[row] = make_int4(i0, i1, i2, 0);
    w_out[row] = make_float4((float)(w0 / den), (float)(w1 / den), (float)(w2 / den), 0.f);
  }
}

// x f32 [16384][512] -> bf16 [16384][512] (gather source, L2-resident per XCD)
__global__ __launch_bounds__(256) void convert_x(
    const float* __restrict__ x, ushort* __restrict__ xbf)
{
  const int id = blockIdx.x * 256 + threadIdx.x;   // one float4 each
#pragma unroll
  for (int it = 0; it < 4; ++it) {
    const int i = id + it * 524288;                // 2097152 float4s total
    const float4 v = *(const float4*)(x + (size_t)i * 4);
    ushort4 o = { f2bf(v.x), f2bf(v.y), f2bf(v.z), f2bf(v.w) };
    *(ushort4*)(xbf + (size_t)i * 4) = o;
  }
}

// Both W1 [768x512] and W2 [512x512] f32 -> transposed bf16 in one launch.
__global__ __launch_bounds__(256) void convert_wt_both(
    const float* __restrict__ W1, const float* __restrict__ W2,
    ushort* __restrict__ W1t, ushort* __restrict__ W2t)
{
  const int id = blockIdx.x * 256 + threadIdx.x;
  if (id < 768 * 512) {
    const int n = id / 768, k = id - n * 768;      // W1t[n][k] = W1[k][n]
    W1t[id] = f2bf(W1[(size_t)k * 512 + n]);
  } else {
    const int id2 = id - 768 * 512;
    if (id2 < 512 * 512) {
      const int n = id2 >> 9, k = id2 & 511;       // W2t[n][k] = W2[k][n]
      W2t[id2] = f2bf(W2[(size_t)k * 512 + n]);
    }
  }
}

// ---------------------------------------------------------------------------
// GEMM1 with FUSED interp+skip A-operand: h2 = relu(hcat @ W1 + b1) where
// hcat[r] = [sum_j w_j*xbf[id_j[r]] (512) | bf16(xs[r]) (256)] is NEVER
// materialized. 256x256 tile, BK=64, NT=12: kt<8 -> gather+combine A-tile,
// kt>=8 -> xs f32->bf16 A-tile. Reg-staged A with direct swizzled ds_write;
// B via global_load_lds (pre-swizzled source). 8-phase schedule kept.
// ---------------------------------------------------------------------------
__global__ __launch_bounds__(512, 2) void gemm1_fused(
    const ushort* __restrict__ xbf, const float* __restrict__ xs,
    const int4* __restrict__ idx3, const float4* __restrict__ w3,
    const ushort* __restrict__ Bt, const float* __restrict__ bias,
    ushort* __restrict__ Cout)
{
  constexpr int K = 768, N = 512, BM = 256, BN = 256, BK = 64, NT = K / BK;
  __shared__ ushort Asm[2][BM * BK];   // 2 x 32 KB
  __shared__ ushort Bsm[2][BN * BK];   // 2 x 32 KB
  const int tid  = threadIdx.x;
  const int lane = tid & 63;
  const int wave = tid >> 6;

  // T1: bijective XCD swizzle (gridDim.x = 512, %8 == 0)
  const int cpx  = gridDim.x >> 3;
  const int wgid = (blockIdx.x & 7) * cpx + (blockIdx.x >> 3);
  const int nbn  = N / BN;                     // 2
  const int bm   = wgid / nbn;
  const int bn   = wgid - bm * nbn;
  const int row0 = bm * BM, col0 = bn * BN;
  const int wr = wave >> 2, wc = wave & 3;     // 2M x 4N wave grid
  const int sbase = wave * 4096 + lane * 16;   // B staging byte base

  // per-thread fused-A assignment: row rl (0..255), half h (64 B of the row)
  const int rl = tid >> 1, h = tid & 1;
  const int gr = row0 + rl;
  const int4 id = idx3[gr];
  const float4 wv = w3[gr];
  const ushort* xb = xbf + (size_t)(gr >> 12) * 524288;
  const ushort* n0 = xb + (size_t)id.x * 512;
  const ushort* n1 = xb + (size_t)id.y * 512;
  const ushort* n2 = xb + (size_t)id.z * 512;
  const float*  sr = xs + (size_t)gr * 256;

  f32x4 acc[8][4] = {};
  short8 ga[4], gb[4], gc[4];   // staging regs (gc unused on xs path)

  auto issueA = [&](int kt) {
    if (kt < 8) {
      const ushort* p0 = n0 + kt * 64 + h * 32;
      const ushort* p1 = n1 + kt * 64 + h * 32;
      const ushort* p2 = n2 + kt * 64 + h * 32;
#pragma unroll
      for (int q = 0; q < 4; ++q) {
        ga[q] = *(const short8*)(p0 + q * 8);
        gb[q] = *(const short8*)(p1 + q * 8);
        gc[q] = *(const short8*)(p2 + q * 8);
      }
    } else {
      const float* s0 = sr + (kt - 8) * 64 + h * 32;
#pragma unroll
      for (int q = 0; q < 4; ++q) {
        ga[q] = *(const short8*)(s0 + q * 4);        // f32 elems q*4..+3
        gb[q] = *(const short8*)(s0 + 16 + q * 4);   // f32 elems 16+q*4..+3
      }
    }
  };
  auto writeA = [&](int buf, int kt) {
    char* base = (char*)&Asm[buf][0] + rl * 128;
    if (kt < 8) {
#pragma unroll
      for (int q = 0; q < 4; ++q) {
        const int s = h * 4 + q;
        short8 o;
#pragma unroll
        for (int e = 0; e < 8; ++e) {
          const float v = wv.x * bf2f((ushort)ga[q][e])
                        + wv.y * bf2f((ushort)gb[q][e])
                        + wv.z * bf2f((ushort)gc[q][e]);
          o[e] = (short)f2bf(v);
        }
        *(short8*)(base + ((s ^ (rl & 7)) << 4)) = o;
      }
    } else {
#pragma unroll
      for (int q = 0; q < 4; ++q) {
        const int s = h * 4 + q;
        short8 o;
#pragma unroll
        for (int e = 0; e < 8; ++e) {
          const int f = q * 8 + e;                   // f32 index 0..31
          const float v = (f < 16) ? ((const float*)&ga[f >> 2])[f & 3]
                                   : ((const float*)&gb[(f - 16) >> 2])[f & 3];
          o[e] = (short)f2bf(v);
        }
        *(short8*)(base + ((s ^ (rl & 7)) << 4)) = o;
      }
    }
  };
  auto stageB = [&](int buf, int kt) {
#pragma unroll
    for (int i = 0; i < 4; ++i) {
      const int o = sbase + i * 1024;
      const int r = o >> 7, s = (o & 127) >> 4;
      __builtin_amdgcn_global_load_lds(
          (const __attribute__((address_space(1))) void*)(Bt + (size_t)(col0 + r) * K + kt * BK + ((s ^ (r & 7)) << 3)),
          (__attribute__((address_space(3))) void*)((char*)&Bsm[buf][0] + o), 16, 0, 0);
    }
  };
  auto rdA = [&](int buf, int mi, int kk) -> short8 {
    const int ra = wr * 128 + mi * 16 + (lane & 15);
    const int s  = kk * 4 + (lane >> 4);
    return *(const short8*)((const char*)&Asm[buf][0] + ra * 128 + ((s ^ (ra & 7)) << 4));
  };
  auto rdB = [&](int buf, int ni, int kk) -> short8 {
    const int rb = wc * 64 + ni * 16 + (lane & 15);
    const int s  = kk * 4 + (lane >> 4);
    return *(const short8*)((const char*)&Bsm[buf][0] + rb * 128 + ((s ^ (rb & 7)) << 4));
  };

  // prologue: tile 0 staged (A via reg-combine, B via global_load_lds)
  issueA(0);
  stageB(0, 0);
  asm volatile("s_waitcnt vmcnt(0)" ::: "memory");
  writeA(0, 0);
  asm volatile("s_waitcnt lgkmcnt(0)" ::: "memory");
  __builtin_amdgcn_s_barrier();

  int cur = 0;
#pragma unroll 1
  for (int t = 0; t < NT; ++t) {
    short8 av[4], bv[4];
    // ---- phase 0: kk=0, mi 0..3 (+ issue all t+1 staging loads) ----
#pragma unroll
    for (int mi = 0; mi < 4; ++mi) av[mi] = rdA(cur, mi, 0);
#pragma unroll
    for (int ni = 0; ni < 4; ++ni) bv[ni] = rdB(cur, ni, 0);
    if (t + 1 < NT) { stageB(cur ^ 1, t + 1); issueA(t + 1); }
    __builtin_amdgcn_s_barrier();
    asm volatile("s_waitcnt lgkmcnt(0)" ::: "memory");
    __builtin_amdgcn_sched_barrier(0);
    __builtin_amdgcn_s_setprio(1);
#pragma unroll
    for (int mi = 0; mi < 4; ++mi)
#pragma unroll
      for (int ni = 0; ni < 4; ++ni)
        acc[mi][ni] = __builtin_amdgcn_mfma_f32_16x16x32_bf16(av[mi], bv[ni], acc[mi][ni], 0, 0, 0);
    __builtin_amdgcn_s_setprio(0);
    __builtin_amdgcn_s_barrier();
    // ---- phase 1: kk=0, mi 4..7 ----
#pragma unroll
    for (int mi = 0; mi < 4; ++mi) av[mi] = rdA(cur, 4 + mi, 0);
    __builtin_amdgcn_s_barrier();
    asm volatile("s_waitcnt lgkmcnt(0)" ::: "memory");
    __builtin_amdgcn_sched_barrier(0);
    __builtin_amdgcn_s_setprio(1);
#pragma unroll
    for (int mi = 0; mi < 4; ++mi)
#pragma unroll
      for (int ni = 0; ni < 4; ++ni)
        acc[4 + mi][ni] = __builtin_amdgcn_mfma_f32_16x16x32_bf16(av[mi], bv[ni], acc[4 + mi][ni], 0, 0, 0);
    __builtin_amdgcn_s_setprio(0);
    __builtin_amdgcn_s_barrier();
    // ---- phase 2: kk=1, mi 0..3 ----
#pragma unroll
    for (int mi = 0; mi < 4; ++mi) av[mi] = rdA(cur, mi, 1);
#pragma unroll
    for (int ni = 0; ni < 4; ++ni) bv[ni] = rdB(cur, ni, 1);
    __builtin_amdgcn_s_barrier();
    asm volatile("s_waitcnt lgkmcnt(0)" ::: "memory");
    __builtin_amdgcn_sched_barrier(0);
    __builtin_amdgcn_s_setprio(1);
#pragma unroll
    for (int mi = 0; mi < 4; ++mi)
#pragma unroll
      for (int ni = 0; ni < 4; ++ni)
        acc[mi][ni] = __builtin_amdgcn_mfma_f32_16x16x32_bf16(av[mi], bv[ni], acc[mi][ni], 0, 0, 0);
    __builtin_amdgcn_s_setprio(0);
    __builtin_amdgcn_s_barrier();
    // ---- phase 3: kk=1, mi 4..7; then combine+write A(t+1) ----
#pragma unroll
    for (int mi = 0; mi < 4; ++mi) av[mi] = rdA(cur, 4 + mi, 1);
    __builtin_amdgcn_s_barrier();
    asm volatile("s_waitcnt lgkmcnt(0)" ::: "memory");
    __builtin_amdgcn_sched_barrier(0);
    __builtin_amdgcn_s_setprio(1);
#pragma unroll
    for (int mi = 0; mi < 4; ++mi)
#pragma unroll
      for (int ni = 0; ni < 4; ++ni)
        acc[4 + mi][ni] = __builtin_amdgcn_mfma_f32_16x16x32_bf16(av[mi], bv[ni], acc[4 + mi][ni], 0, 0, 0);
    __builtin_amdgcn_s_setprio(0);
    if (t + 1 < NT) {
      asm volatile("s_waitcnt vmcnt(0)" ::: "memory");  // gather + B-lds landed
      writeA(cur ^ 1, t + 1);
      asm volatile("s_waitcnt lgkmcnt(0)" ::: "memory");
    }
    __builtin_amdgcn_s_barrier();
    cur ^= 1;
  }

  // epilogue: bias + relu -> bf16; C/D: col = lane&15, row = (lane>>4)*4 + reg
  const int lc = lane & 15, lr = lane >> 4;
#pragma unroll
  for (int mi = 0; mi < 8; ++mi) {
#pragma unroll
    for (int ni = 0; ni < 4; ++ni) {
      const int col = col0 + wc * 64 + ni * 16 + lc;
      const float bv2 = bias[col];
      const int rbase = row0 + wr * 128 + mi * 16 + lr * 4;
#pragma unroll
      for (int r = 0; r < 4; ++r) {
        float v = acc[mi][ni][r] + bv2;
        v = v > 0.f ? v : 0.f;
        Cout[(size_t)(rbase + r) * N + col] = f2bf(v);
      }
    }
  }
}

// ---------------------------------------------------------------------------
// GEMM2 (unchanged 8-phase template): out = relu(h2 @ W2 + b2), f32 out.
// ---------------------------------------------------------------------------
template<int K, bool OUT_BF16>
__global__ __launch_bounds__(512, 2) void gemm_bias_relu(
    const ushort* __restrict__ A, const ushort* __restrict__ Bt,
    const float* __restrict__ bias, void* __restrict__ Cout, int M, int N)
{
  constexpr int BM = 256, BN = 256, BK = 64, NT = K / BK;
  __shared__ ushort Asm[2][BM * BK];
  __shared__ ushort Bsm[2][BN * BK];
  const int tid  = threadIdx.x;
  const int lane = tid & 63;
  const int wave = tid >> 6;

  const int cpx  = gridDim.x >> 3;
  const int wgid = (blockIdx.x & 7) * cpx + (blockIdx.x >> 3);
  const int nbn  = N / BN;
  const int bm   = wgid / nbn;
  const int bn   = wgid - bm * nbn;
  const int row0 = bm * BM, col0 = bn * BN;
  const int wr = wave >> 2, wc = wave & 3;
  const int sbase = wave * 4096 + lane * 16;

  f32x4 acc[8][4] = {};

  auto stageA = [&](int buf, int kt) {
#pragma unroll
    for (int i = 0; i < 4; ++i) {
      const int o = sbase + i * 1024;
      const int r = o >> 7, s = (o & 127) >> 4;
      __builtin_amdgcn_global_load_lds(
          (const __attribute__((address_space(1))) void*)(A + (size_t)(row0 + r) * K + kt * BK + ((s ^ (r & 7)) << 3)),
          (__attribute__((address_space(3))) void*)((char*)&Asm[buf][0] + o), 16, 0, 0);
    }
  };
  auto stageB = [&](int buf, int kt) {
#pragma unroll
    for (int i = 0; i < 4; ++i) {
      const int o = sbase + i * 1024;
      const int r = o >> 7, s = (o & 127) >> 4;
      __builtin_amdgcn_global_load_lds(
          (const __attribute__((address_space(1))) void*)(Bt + (size_t)(col0 + r) * K + kt * BK + ((s ^ (r & 7)) << 3)),
          (__attribute__((address_space(3))) void*)((char*)&Bsm[buf][0] + o), 16, 0, 0);
    }
  };
  auto rdA = [&](int buf, int mi, int kk) -> short8 {
    const int ra = wr * 128 + mi * 16 + (lane & 15);
    const int s  = kk * 4 + (lane >> 4);
    return *(const short8*)((const char*)&Asm[buf][0] + ra * 128 + ((s ^ (ra & 7)) << 4));
  };
  auto rdB = [&](int buf, int ni, int kk) -> short8 {
    const int rb = wc * 64 + ni * 16 + (lane & 15);
    const int s  = kk * 4 + (lane >> 4);
    return *(const short8*)((const char*)&Bsm[buf][0] + rb * 128 + ((s ^ (rb & 7)) << 4));
  };

  stageA(0, 0); stageB(0, 0);
  asm volatile("s_waitcnt vmcnt(0)" ::: "memory");
  __builtin_amdgcn_s_barrier();

  int cur = 0;
#pragma unroll 1
  for (int t = 0; t < NT; ++t) {
    short8 av[4], bv[4];
#pragma unroll
    for (int mi = 0; mi < 4; ++mi) av[mi] = rdA(cur, mi, 0);
#pragma unroll
    for (int ni = 0; ni < 4; ++ni) bv[ni] = rdB(cur, ni, 0);
    if (t + 1 < NT) stageA(cur ^ 1, t + 1);
    __builtin_amdgcn_s_barrier();
    asm volatile("s_waitcnt lgkmcnt(0)" ::: "memory");
    __builtin_amdgcn_sched_barrier(0);
    __builtin_amdgcn_s_setprio(1);
#pragma unroll
    for (int mi = 0; mi < 4; ++mi)
#pragma unroll
      for (int ni = 0; ni < 4; ++ni)
        acc[mi][ni] = __builtin_amdgcn_mfma_f32_16x16x32_bf16(av[mi], bv[ni], acc[mi][ni], 0, 0, 0);
    __builtin_amdgcn_s_setprio(0);
    __builtin_amdgcn_s_barrier();
#pragma unroll
    for (int mi = 0; mi < 4; ++mi) av[mi] = rdA(cur, 4 + mi, 0);
    if (t + 1 < NT) stageB(cur ^ 1, t + 1);
    __builtin_amdgcn_s_barrier();
    asm volatile("s_waitcnt lgkmcnt(0)" ::: "memory");
    __builtin_amdgcn_sched_barrier(0);
    __builtin_amdgcn_s_setprio(1);
#pragma unroll
    for (int mi = 0; mi < 4; ++mi)
#pragma unroll
      for (int ni = 0; ni < 4; ++ni)
        acc[4 + mi][ni] = __builtin_amdgcn_mfma_f32_16x16x32_bf16(av[mi], bv[ni], acc[4 + mi][ni], 0, 0, 0);
    __builtin_amdgcn_s_setprio(0);
    __builtin_amdgcn_s_barrier();
#pragma unroll
    for (int mi = 0; mi < 4; ++mi) av[mi] = rdA(cur, mi, 1);
#pragma unroll
    for (int ni = 0; ni < 4; ++ni) bv[ni] = rdB(cur, ni, 1);
    __builtin_amdgcn_s_barrier();
    asm volatile("s_waitcnt lgkmcnt(0)" ::: "memory");
    __builtin_amdgcn_sched_barrier(0);
    __builtin_amdgcn_s_setprio(1);
#pragma unroll
    for (int mi = 0; mi < 4; ++mi)
#pragma unroll
      for (int ni = 0; ni < 4; ++ni)
        acc[mi][ni] = __builtin_amdgcn_mfma_f32_16x16x32_bf16(av[mi], bv[ni], acc[mi][ni], 0, 0, 0);
    __builtin_amdgcn_s_setprio(0);
    __builtin_amdgcn_s_barrier();
#pragma unroll
    for (int mi = 0; mi < 4; ++mi) av[mi] = rdA(cur, 4 + mi, 1);
    __builtin_amdgcn_s_barrier();
    asm volatile("s_waitcnt lgkmcnt(0)" ::: "memory");
    __builtin_amdgcn_sched_barrier(0);
    __builtin_amdgcn_s_setprio(1);
#pragma unroll
    for (int mi = 0; mi < 4; ++mi)
#pragma unroll
      for (int ni = 0; ni < 4; ++ni)
        acc[4 + mi][ni] = __builtin_amdgcn_mfma_f32_16x16x32_bf16(av[mi], bv[ni], acc[4 + mi][ni], 0, 0, 0);
    __builtin_amdgcn_s_setprio(0);
    asm volatile("s_waitcnt vmcnt(0)" ::: "memory");
    __builtin_amdgcn_s_barrier();
    cur ^= 1;
  }

  const int lc = lane & 15, lr = lane >> 4;
#pragma unroll
  for (int mi = 0; mi < 8; ++mi) {
#pragma unroll
    for (int ni = 0; ni < 4; ++ni) {
      const int col = col0 + wc * 64 + ni * 16 + lc;
      const float bv2 = bias[col];
      const int rbase = row0 + wr * 128 + mi * 16 + lr * 4;
#pragma unroll
      for (int r = 0; r < 4; ++r) {
        float v = acc[mi][ni][r] + bv2;
        v = v > 0.f ? v : 0.f;
        if (OUT_BF16) ((ushort*)Cout)[(size_t)(rbase + r) * N + col] = f2bf(v);
        else          ((float*)Cout)[(size_t)(rbase + r) * N + col] = v;
      }
    }
  }
}

// ---------------------------------------------------------------------------
extern "C" void kernel_launch(void* const* d_in, const int* in_sizes, int n_in,
                              void* d_out, int out_size, void* d_ws, size_t ws_size,
                              hipStream_t stream) {
  const float* x        = (const float*)d_in[0];   // [16384, 512]
  const float* pos      = (const float*)d_in[1];   // [16384, 3]
  const float* x_skip   = (const float*)d_in[3];   // [65536, 256]
  const float* pos_skip = (const float*)d_in[4];   // [65536, 3]
  const float* W1       = (const float*)d_in[6];   // [768, 512]
  const float* b1       = (const float*)d_in[7];   // [512]
  const float* W2       = (const float*)d_in[8];   // [512, 512]
  const float* b2       = (const float*)d_in[9];   // [512]

  // d_out doubles as scratch for xbf (16.8 MB): fully consumed by gemm1_fused
  // before GEMM2 overwrites d_out with the final f32 output.
  ushort* xbf  = (ushort*)d_out;                       // [16384][512] bf16

  char* ws = (char*)d_ws;
  ushort* h2   = (ushort*)ws;                          // [65536][512] bf16, 67108864 B
  ushort* W1t  = (ushort*)(ws + 67108864);             // [512][768]  bf16, 786432 B
  ushort* W2t  = (ushort*)(ws + 67895296);             // [512][512]  bf16, 524288 B
  int4*   idx3 = (int4*)  (ws + 68419584);             // [65536] int4, 1 MB
  float4* w3   = (float4*)(ws + 69468160);             // [65536] float4, 1 MB

  knn_kernel<<<1024, 256, 0, stream>>>(pos, pos_skip, idx3, w3);
  convert_x<<<2048, 256, 0, stream>>>(x, xbf);
  convert_wt_both<<<(768 * 512 + 512 * 512 + 255) / 256, 256, 0, stream>>>(W1, W2, W1t, W2t);

  // GEMM1 (fused interp+skip A): -> h2 bf16; grid = 256 x 2 = 512
  gemm1_fused<<<512, 512, 0, stream>>>(xbf, x_skip, idx3, w3, W1t, b1, h2);
  // GEMM2: [65536x512] x [512x512] -> d_out f32
  gemm_bias_relu<512, false><<<512, 512, 0, stream>>>(h2, W2t, b2, d_out, 65536, 512);
}

// Round 10
// 224.788 us; speedup vs baseline: 1.1373x; 1.1373x over previous
//
#include <hip/hip_runtime.h>
#include <stdint.h>

typedef __attribute__((ext_vector_type(8))) short short8;
typedef __attribute__((ext_vector_type(4))) float f32x4;

static __device__ __forceinline__ ushort f2bf(float f) {
  uint32_t u = __float_as_uint(f);
  uint32_t r = (u + 0x7FFFu + ((u >> 16) & 1u)) >> 16;
  return (ushort)r;
}
static __device__ __forceinline__ float bf2f(ushort h) {
  return __uint_as_float(((uint32_t)h) << 16);
}

// ---------------------------------------------------------------------------
// KNN top-3, f64-exact selection, branchless insert. 4 threads/point.
// ---------------------------------------------------------------------------
static __device__ __forceinline__ void ins3b(double d, int i,
    double& b0, double& b1, double& b2, int& i0, int& i1, int& i2) {
  const bool c0 = d < b0, c1 = d < b1, c2 = d < b2;
  const double nb0 = c0 ? d : b0;
  const int    ni0 = c0 ? i : i0;
  const double nb1 = c0 ? b0 : (c1 ? d : b1);
  const int    ni1 = c0 ? i0 : (c1 ? i : i1);
  const double nb2 = c1 ? b1 : (c2 ? d : b2);
  const int    ni2 = c1 ? i1 : (c2 ? i : i2);
  b0 = nb0; b1 = nb1; b2 = nb2; i0 = ni0; i1 = ni1; i2 = ni2;
}

__global__ __launch_bounds__(256) void knn_kernel(
    const float* __restrict__ pos, const float* __restrict__ pos_skip,
    int4* __restrict__ idx_out, float4* __restrict__ w_out)
{
  __shared__ float pc[3072];
  const int b   = blockIdx.x >> 6;      // 64 blocks per batch
  const int blk = blockIdx.x & 63;      // 64 fine points per block
  for (int j = threadIdx.x; j < 3072; j += 256) pc[j] = pos[b * 3072 + j];
  __syncthreads();

  const int p   = threadIdx.x >> 2;     // point within block (0..63)
  const int sub = threadIdx.x & 3;      // candidate slice   (0..3)
  const int row = b * 4096 + blk * 64 + p;
  const double px = (double)pos_skip[(size_t)row * 3 + 0];
  const double py = (double)pos_skip[(size_t)row * 3 + 1];
  const double pz = (double)pos_skip[(size_t)row * 3 + 2];

  double b0 = 1e300, b1 = 1e300, b2 = 1e300;
  int i0 = 0, i1 = 0, i2 = 0;
#pragma unroll 4
  for (int j = 0; j < 256; ++j) {
    const int i = j * 4 + sub;
    const double dx = (double)pc[i * 3 + 0] - px;
    const double dy = (double)pc[i * 3 + 1] - py;
    const double dz = (double)pc[i * 3 + 2] - pz;
    const double d = dx * dx + dy * dy + dz * dz;
    ins3b(d, i, b0, b1, b2, i0, i1, i2);
  }
#pragma unroll
  for (int m = 1; m <= 2; m <<= 1) {
    const double c0 = __shfl_xor(b0, m), c1 = __shfl_xor(b1, m), c2 = __shfl_xor(b2, m);
    const int    j0 = __shfl_xor(i0, m), j1 = __shfl_xor(i1, m), j2 = __shfl_xor(i2, m);
    ins3b(c0, j0, b0, b1, b2, i0, i1, i2);
    ins3b(c1, j1, b0, b1, b2, i0, i1, i2);
    ins3b(c2, j2, b0, b1, b2, i0, i1, i2);
  }
  if (sub == 0) {
    const double w0 = 1.0 / (sqrt(b0) + 1e-8);
    const double w1 = 1.0 / (sqrt(b1) + 1e-8);
    const double w2 = 1.0 / (sqrt(b2) + 1e-8);
    const double den = w0 + w1 + w2 + 1e-8;
    idx_out[row] = make_int4(i0, i1, i2, 0);
    w_out[row] = make_float4((float)(w0 / den), (float)(w1 / den), (float)(w2 / den), 0.f);
  }
}

// ---------------------------------------------------------------------------
// Merged conversions: x f32->bf16 (blocks 0..2047), W1/W2 f32 -> transposed
// bf16 (blocks 2048..4607). One launch instead of two.
// ---------------------------------------------------------------------------
__global__ __launch_bounds__(256) void convert_all(
    const float* __restrict__ x, const float* __restrict__ W1,
    const float* __restrict__ W2, ushort* __restrict__ xbf,
    ushort* __restrict__ W1t, ushort* __restrict__ W2t)
{
  if (blockIdx.x < 2048) {
    const int id = blockIdx.x * 256 + threadIdx.x;   // one float4 per iter
#pragma unroll
    for (int it = 0; it < 4; ++it) {
      const int i = id + it * 524288;                // 2097152 float4s total
      const float4 v = *(const float4*)(x + (size_t)i * 4);
      ushort4 o = { f2bf(v.x), f2bf(v.y), f2bf(v.z), f2bf(v.w) };
      *(ushort4*)(xbf + (size_t)i * 4) = o;
    }
  } else {
    const int id = (blockIdx.x - 2048) * 256 + threadIdx.x;
    if (id < 768 * 512) {
      const int n = id / 768, k = id - n * 768;      // W1t[n][k] = W1[k][n]
      W1t[id] = f2bf(W1[(size_t)k * 512 + n]);
    } else {
      const int id2 = id - 768 * 512;
      if (id2 < 512 * 512) {
        const int n = id2 >> 9, k = id2 & 511;       // W2t[n][k] = W2[k][n]
        W2t[id2] = f2bf(W2[(size_t)k * 512 + n]);
      }
    }
  }
}

// ---------------------------------------------------------------------------
// Fused gather-interp (bf16 gathers) + skip-copy. Depth-4: ALL 4 rows' loads
// issued before any compute (xs HBM loads first — longest latency), ~16 loads
// in flight per thread. Named structs only (no runtime-indexed register
// arrays). 4 rows/wave, XCD-batch affinity.
// ---------------------------------------------------------------------------
struct G3 { short8 g0, g1, g2; };

__global__ __launch_bounds__(256) void interp_gather_fused(
    const ushort* __restrict__ xbf, const float* __restrict__ xs,
    const int4* __restrict__ idx3, const float4* __restrict__ w3,
    ushort* __restrict__ hcat)
{
  const int xcd  = blockIdx.x & 7;
  const int j    = blockIdx.x >> 3;                  // 0..511 within xcd
  const int widx = j * 4 + (threadIdx.x >> 6);       // 0..2047 within xcd
  const int lane = threadIdx.x & 63;
  const int rbase = xcd * 8192 + widx * 4;           // 4 consecutive rows/wave

  int4   ids[4];
  float4 wts[4];
#pragma unroll
  for (int k = 0; k < 4; ++k) { ids[k] = idx3[rbase + k]; wts[k] = w3[rbase + k]; }

  const int b = rbase >> 12;                         // same batch for all 4 rows
  const ushort* xb = xbf + (size_t)b * 1024 * 512;

  // HBM skip loads first (longest latency)
  float4 s0 = *(const float4*)(xs + (size_t)(rbase + 0) * 256 + lane * 4);
  float4 s1 = *(const float4*)(xs + (size_t)(rbase + 1) * 256 + lane * 4);
  float4 s2 = *(const float4*)(xs + (size_t)(rbase + 2) * 256 + lane * 4);
  float4 s3 = *(const float4*)(xs + (size_t)(rbase + 3) * 256 + lane * 4);

  G3 r0, r1, r2, r3;
  auto loadg = [&](int k, G3& r) {
    r.g0 = *(const short8*)(xb + (size_t)ids[k].x * 512 + lane * 8);
    r.g1 = *(const short8*)(xb + (size_t)ids[k].y * 512 + lane * 8);
    r.g2 = *(const short8*)(xb + (size_t)ids[k].z * 512 + lane * 8);
  };
  loadg(0, r0); loadg(1, r1); loadg(2, r2); loadg(3, r3);
  __builtin_amdgcn_sched_barrier(0);

  auto comp = [&](int k, const G3& r, const float4& s) {
    const float4 w = wts[k];
    ushort* orow = hcat + (size_t)(rbase + k) * 768;
    short8 o;
#pragma unroll
    for (int e = 0; e < 8; ++e) {
      const float v = w.x * bf2f((ushort)r.g0[e])
                    + w.y * bf2f((ushort)r.g1[e])
                    + w.z * bf2f((ushort)r.g2[e]);
      o[e] = (short)f2bf(v);
    }
    *(short8*)(orow + lane * 8) = o;
    ushort4 o2 = { f2bf(s.x), f2bf(s.y), f2bf(s.z), f2bf(s.w) };
    *(ushort4*)(orow + 512 + lane * 4) = o2;
  };
  comp(0, r0, s0); comp(1, r1, s1); comp(2, r2, s2); comp(3, r3, s3);
}

// ---------------------------------------------------------------------------
// 256x256 8-phase bf16 MFMA GEMM (T1+T2+T3+T4+T5): C = relu(A*Bt^T + bias).
// 8 waves (2M x 4N), BK=64, 2-deep LDS double-buffer (128 KB), raw barriers,
// counted-vmcnt pipeline. XOR-swizzled LDS (both-sides involution).
// ---------------------------------------------------------------------------
template<int K, bool OUT_BF16>
__global__ __launch_bounds__(512, 2) void gemm_bias_relu(
    const ushort* __restrict__ A, const ushort* __restrict__ Bt,
    const float* __restrict__ bias, void* __restrict__ Cout, int M, int N)
{
  constexpr int BM = 256, BN = 256, BK = 64, NT = K / BK;
  __shared__ ushort Asm[2][BM * BK];   // 2 x 32 KB
  __shared__ ushort Bsm[2][BN * BK];   // 2 x 32 KB
  const int tid  = threadIdx.x;
  const int lane = tid & 63;
  const int wave = tid >> 6;

  // T1: bijective XCD swizzle (gridDim.x % 8 == 0)
  const int cpx  = gridDim.x >> 3;
  const int wgid = (blockIdx.x & 7) * cpx + (blockIdx.x >> 3);
  const int nbn  = N / BN;
  const int bm   = wgid / nbn;
  const int bn   = wgid - bm * nbn;
  const int row0 = bm * BM, col0 = bn * BN;
  const int wr = wave >> 2, wc = wave & 3;     // 2M x 4N wave grid
  const int sbase = wave * 4096 + lane * 16;   // staging byte base (4KB/wave)

  f32x4 acc[8][4] = {};

  // T2 swizzle: LDS 16B slot (r, s) holds global slot (s ^ (r&7)).
  auto stageA = [&](int buf, int kt) {
#pragma unroll
    for (int i = 0; i < 4; ++i) {
      const int o = sbase + i * 1024;          // linear LDS byte offset
      const int r = o >> 7, s = (o & 127) >> 4;
      __builtin_amdgcn_global_load_lds(
          (const __attribute__((address_space(1))) void*)(A + (size_t)(row0 + r) * K + kt * BK + ((s ^ (r & 7)) << 3)),
          (__attribute__((address_space(3))) void*)((char*)&Asm[buf][0] + o), 16, 0, 0);
    }
  };
  auto stageB = [&](int buf, int kt) {
#pragma unroll
    for (int i = 0; i < 4; ++i) {
      const int o = sbase + i * 1024;
      const int r = o >> 7, s = (o & 127) >> 4;
      __builtin_amdgcn_global_load_lds(
          (const __attribute__((address_space(1))) void*)(Bt + (size_t)(col0 + r) * K + kt * BK + ((s ^ (r & 7)) << 3)),
          (__attribute__((address_space(3))) void*)((char*)&Bsm[buf][0] + o), 16, 0, 0);
    }
  };
  auto rdA = [&](int buf, int mi, int kk) -> short8 {
    const int ra = wr * 128 + mi * 16 + (lane & 15);
    const int s  = kk * 4 + (lane >> 4);
    return *(const short8*)((const char*)&Asm[buf][0] + ra * 128 + ((s ^ (ra & 7)) << 4));
  };
  auto rdB = [&](int buf, int ni, int kk) -> short8 {
    const int rb = wc * 64 + ni * 16 + (lane & 15);
    const int s  = kk * 4 + (lane >> 4);
    return *(const short8*)((const char*)&Bsm[buf][0] + rb * 128 + ((s ^ (rb & 7)) << 4));
  };

  // prologue: tile 0 fully staged and landed
  stageA(0, 0); stageB(0, 0);
  asm volatile("s_waitcnt vmcnt(0)" ::: "memory");
  __builtin_amdgcn_s_barrier();

  int cur = 0;
#pragma unroll 1
  for (int t = 0; t < NT; ++t) {
    short8 av[4], bv[4];
    // ---- phase 0: kk=0, mi 0..3 (+ stage A of t+1) ----
#pragma unroll
    for (int mi = 0; mi < 4; ++mi) av[mi] = rdA(cur, mi, 0);
#pragma unroll
    for (int ni = 0; ni < 4; ++ni) bv[ni] = rdB(cur, ni, 0);
    if (t + 1 < NT) stageA(cur ^ 1, t + 1);
    __builtin_amdgcn_s_barrier();
    asm volatile("s_waitcnt lgkmcnt(0)" ::: "memory");
    __builtin_amdgcn_sched_barrier(0);
    __builtin_amdgcn_s_setprio(1);
#pragma unroll
    for (int mi = 0; mi < 4; ++mi)
#pragma unroll
      for (int ni = 0; ni < 4; ++ni)
        acc[mi][ni] = __builtin_amdgcn_mfma_f32_16x16x32_bf16(av[mi], bv[ni], acc[mi][ni], 0, 0, 0);
    __builtin_amdgcn_s_setprio(0);
    __builtin_amdgcn_s_barrier();
    // ---- phase 1: kk=0, mi 4..7 (+ stage B of t+1) ----
#pragma unroll
    for (int mi = 0; mi < 4; ++mi) av[mi] = rdA(cur, 4 + mi, 0);
    if (t + 1 < NT) stageB(cur ^ 1, t + 1);
    __builtin_amdgcn_s_barrier();
    asm volatile("s_waitcnt lgkmcnt(0)" ::: "memory");
    __builtin_amdgcn_sched_barrier(0);
    __builtin_amdgcn_s_setprio(1);
#pragma unroll
    for (int mi = 0; mi < 4; ++mi)
#pragma unroll
      for (int ni = 0; ni < 4; ++ni)
        acc[4 + mi][ni] = __builtin_amdgcn_mfma_f32_16x16x32_bf16(av[mi], bv[ni], acc[4 + mi][ni], 0, 0, 0);
    __builtin_amdgcn_s_setprio(0);
    __builtin_amdgcn_s_barrier();
    // ---- phase 2: kk=1, mi 0..3 ----
#pragma unroll
    for (int mi = 0; mi < 4; ++mi) av[mi] = rdA(cur, mi, 1);
#pragma unroll
    for (int ni = 0; ni < 4; ++ni) bv[ni] = rdB(cur, ni, 1);
    __builtin_amdgcn_s_barrier();
    asm volatile("s_waitcnt lgkmcnt(0)" ::: "memory");
    __builtin_amdgcn_sched_barrier(0);
    __builtin_amdgcn_s_setprio(1);
#pragma unroll
    for (int mi = 0; mi < 4; ++mi)
#pragma unroll
      for (int ni = 0; ni < 4; ++ni)
        acc[mi][ni] = __builtin_amdgcn_mfma_f32_16x16x32_bf16(av[mi], bv[ni], acc[mi][ni], 0, 0, 0);
    __builtin_amdgcn_s_setprio(0);
    __builtin_amdgcn_s_barrier();
    // ---- phase 3: kk=1, mi 4..7 (+ vmcnt drain for t+1 at end) ----
#pragma unroll
    for (int mi = 0; mi < 4; ++mi) av[mi] = rdA(cur, 4 + mi, 1);
    __builtin_amdgcn_s_barrier();
    asm volatile("s_waitcnt lgkmcnt(0)" ::: "memory");
    __builtin_amdgcn_sched_barrier(0);
    __builtin_amdgcn_s_setprio(1);
#pragma unroll
    for (int mi = 0; mi < 4; ++mi)
#pragma unroll
      for (int ni = 0; ni < 4; ++ni)
        acc[4 + mi][ni] = __builtin_amdgcn_mfma_f32_16x16x32_bf16(av[mi], bv[ni], acc[4 + mi][ni], 0, 0, 0);
    __builtin_amdgcn_s_setprio(0);
    asm volatile("s_waitcnt vmcnt(0)" ::: "memory");  // t+1's stage landed
    __builtin_amdgcn_s_barrier();
    cur ^= 1;
  }

  // epilogue: bias + relu; C/D: col = lane&15, row = (lane>>4)*4 + reg
  const int lc = lane & 15, lr = lane >> 4;
#pragma unroll
  for (int mi = 0; mi < 8; ++mi) {
#pragma unroll
    for (int ni = 0; ni < 4; ++ni) {
      const int col = col0 + wc * 64 + ni * 16 + lc;
      const float bv2 = bias[col];
      const int rbase = row0 + wr * 128 + mi * 16 + lr * 4;
#pragma unroll
      for (int r = 0; r < 4; ++r) {
        float v = acc[mi][ni][r] + bv2;
        v = v > 0.f ? v : 0.f;
        if (OUT_BF16) ((ushort*)Cout)[(size_t)(rbase + r) * N + col] = f2bf(v);
        else          ((float*)Cout)[(size_t)(rbase + r) * N + col] = v;
      }
    }
  }
}

// ---------------------------------------------------------------------------
extern "C" void kernel_launch(void* const* d_in, const int* in_sizes, int n_in,
                              void* d_out, int out_size, void* d_ws, size_t ws_size,
                              hipStream_t stream) {
  const float* x        = (const float*)d_in[0];   // [16384, 512]
  const float* pos      = (const float*)d_in[1];   // [16384, 3]
  const float* x_skip   = (const float*)d_in[3];   // [65536, 256]
  const float* pos_skip = (const float*)d_in[4];   // [65536, 3]
  const float* W1       = (const float*)d_in[6];   // [768, 512]
  const float* b1       = (const float*)d_in[7];   // [512]
  const float* W2       = (const float*)d_in[8];   // [512, 512]
  const float* b2       = (const float*)d_in[9];   // [512]

  // d_out (134.2 MB f32) doubles as scratch: hcat bf16 (100.7 MB) + xbf bf16
  // (16.8 MB tail). Both fully consumed before GEMM2 overwrites d_out.
  ushort* hcat = (ushort*)d_out;                       // [65536][768] bf16
  ushort* xbf  = (ushort*)((char*)d_out + 100663296);  // [16384][512] bf16

  char* ws = (char*)d_ws;
  ushort* h2   = (ushort*)ws;                          // [65536][512] bf16, 67108864 B
  ushort* W1t  = (ushort*)(ws + 67108864);             // [512][768]  bf16, 786432 B
  ushort* W2t  = (ushort*)(ws + 67895296);             // [512][512]  bf16, 524288 B
  int4*   idx3 = (int4*)  (ws + 68419584);             // [65536] int4, 1 MB
  float4* w3   = (float4*)(ws + 69468160);             // [65536] float4, 1 MB

  knn_kernel<<<1024, 256, 0, stream>>>(pos, pos_skip, idx3, w3);
  convert_all<<<2048 + 2560, 256, 0, stream>>>(x, W1, W2, xbf, W1t, W2t);
  interp_gather_fused<<<4096, 256, 0, stream>>>(xbf, x_skip, idx3, w3, hcat);

  // GEMM1: [65536x768] x [768x512] -> h2 bf16 (ws); grid = 256 x 2 = 512
  gemm_bias_relu<768, true><<<512, 512, 0, stream>>>(hcat, W1t, b1, (void*)h2, 65536, 512);
  // GEMM2: [65536x512] x [512x512] -> d_out f32
  gemm_bias_relu<512, false><<<512, 512, 0, stream>>>(h2, W2t, b2, d_out, 65536, 512);
}

// Round 11
// 204.599 us; speedup vs baseline: 1.2496x; 1.0987x over previous
//
#include <hip/hip_runtime.h>
#include <stdint.h>

typedef __attribute__((ext_vector_type(8))) short short8;
typedef __attribute__((ext_vector_type(4))) float f32x4;

static __device__ __forceinline__ ushort f2bf(float f) {
  uint32_t u = __float_as_uint(f);
  uint32_t r = (u + 0x7FFFu + ((u >> 16) & 1u)) >> 16;
  return (ushort)r;
}
static __device__ __forceinline__ float bf2f(ushort h) {
  return __uint_as_float(((uint32_t)h) << 16);
}

// ---------------------------------------------------------------------------
// Branchless top-3 insert (select network).
// ---------------------------------------------------------------------------
static __device__ __forceinline__ void ins3b(double d, int i,
    double& b0, double& b1, double& b2, int& i0, int& i1, int& i2) {
  const bool c0 = d < b0, c1 = d < b1, c2 = d < b2;
  const double nb0 = c0 ? d : b0;
  const int    ni0 = c0 ? i : i0;
  const double nb1 = c0 ? b0 : (c1 ? d : b1);
  const int    ni1 = c0 ? i0 : (c1 ? i : i1);
  const double nb2 = c1 ? b1 : (c2 ? d : b2);
  const int    ni2 = c1 ? i1 : (c2 ? i : i2);
  b0 = nb0; b1 = nb1; b2 = nb2; i0 = ni0; i1 = ni1; i2 = ni2;
}

// ---------------------------------------------------------------------------
// prep: blocks 0..1023 = KNN (f64-exact, 4 threads/point);
//       1024..3071  = x f32->bf16;  3072..7167 = x_skip f32->bf16;
//       7168..9727  = W1a/W1b/W2 transposed converts.
// Merged so the VALU-bound KNN overlaps the HBM-bound converts.
// ---------------------------------------------------------------------------
__global__ __launch_bounds__(256) void prep_kernel(
    const float* __restrict__ pos, const float* __restrict__ pos_skip,
    const float* __restrict__ x, const float* __restrict__ xs,
    const float* __restrict__ W1, const float* __restrict__ W2,
    int4* __restrict__ idx_out, float4* __restrict__ w_out,
    ushort* __restrict__ xbf, ushort* __restrict__ xsbf,
    ushort* __restrict__ W1at, ushort* __restrict__ W1bt,
    ushort* __restrict__ W2t)
{
  __shared__ float pc[3072];
  if (blockIdx.x < 1024) {
    const int b   = blockIdx.x >> 6;      // 64 blocks per batch
    const int blk = blockIdx.x & 63;      // 64 fine points per block
    for (int j = threadIdx.x; j < 3072; j += 256) pc[j] = pos[b * 3072 + j];
    __syncthreads();

    const int p   = threadIdx.x >> 2;
    const int sub = threadIdx.x & 3;
    const int row = b * 4096 + blk * 64 + p;
    const double px = (double)pos_skip[(size_t)row * 3 + 0];
    const double py = (double)pos_skip[(size_t)row * 3 + 1];
    const double pz = (double)pos_skip[(size_t)row * 3 + 2];

    double b0 = 1e300, b1 = 1e300, b2 = 1e300;
    int i0 = 0, i1 = 0, i2 = 0;
#pragma unroll 4
    for (int j = 0; j < 256; ++j) {
      const int i = j * 4 + sub;
      const double dx = (double)pc[i * 3 + 0] - px;
      const double dy = (double)pc[i * 3 + 1] - py;
      const double dz = (double)pc[i * 3 + 2] - pz;
      const double d = dx * dx + dy * dy + dz * dz;
      ins3b(d, i, b0, b1, b2, i0, i1, i2);
    }
#pragma unroll
    for (int m = 1; m <= 2; m <<= 1) {
      const double c0 = __shfl_xor(b0, m), c1 = __shfl_xor(b1, m), c2 = __shfl_xor(b2, m);
      const int    j0 = __shfl_xor(i0, m), j1 = __shfl_xor(i1, m), j2 = __shfl_xor(i2, m);
      ins3b(c0, j0, b0, b1, b2, i0, i1, i2);
      ins3b(c1, j1, b0, b1, b2, i0, i1, i2);
      ins3b(c2, j2, b0, b1, b2, i0, i1, i2);
    }
    if (sub == 0) {
      const double w0 = 1.0 / (sqrt(b0) + 1e-8);
      const double w1 = 1.0 / (sqrt(b1) + 1e-8);
      const double w2 = 1.0 / (sqrt(b2) + 1e-8);
      const double den = w0 + w1 + w2 + 1e-8;
      idx_out[row] = make_int4(i0, i1, i2, 0);
      w_out[row] = make_float4((float)(w0 / den), (float)(w1 / den), (float)(w2 / den), 0.f);
    }
  } else if (blockIdx.x < 3072) {
    const int id = (blockIdx.x - 1024) * 256 + threadIdx.x;   // x: 2,097,152 f4
#pragma unroll
    for (int it = 0; it < 4; ++it) {
      const int i = id + it * 524288;
      const float4 v = *(const float4*)(x + (size_t)i * 4);
      ushort4 o = { f2bf(v.x), f2bf(v.y), f2bf(v.z), f2bf(v.w) };
      *(ushort4*)(xbf + (size_t)i * 4) = o;
    }
  } else if (blockIdx.x < 7168) {
    const int id = (blockIdx.x - 3072) * 256 + threadIdx.x;   // xs: 4,194,304 f4
#pragma unroll
    for (int it = 0; it < 4; ++it) {
      const int i = id + it * 1048576;
      const float4 v = *(const float4*)(xs + (size_t)i * 4);
      ushort4 o = { f2bf(v.x), f2bf(v.y), f2bf(v.z), f2bf(v.w) };
      *(ushort4*)(xsbf + (size_t)i * 4) = o;
    }
  } else {
    const int id = (blockIdx.x - 7168) * 256 + threadIdx.x;
    if (id < 262144) {                       // W1at[n][k] = W1[k][n], k<512
      const int n = id >> 9, k = id & 511;
      W1at[id] = f2bf(W1[(size_t)k * 512 + n]);
    } else if (id < 393216) {                // W1bt[n][k] = W1[512+k][n], k<256
      const int id2 = id - 262144;
      const int n = id2 >> 8, k = id2 & 255;
      W1bt[id2] = f2bf(W1[(size_t)(512 + k) * 512 + n]);
    } else if (id < 655360) {                // W2t[n][k] = W2[k][n]
      const int id3 = id - 393216;
      const int n = id3 >> 9, k = id3 & 511;
      W2t[id3] = f2bf(W2[(size_t)k * 512 + n]);
    }
  }
}

// ---------------------------------------------------------------------------
// combine: h2[r] = relu( w.x*Y[id.x] + w.y*Y[id.y] + w.z*Y[id.z] + S[r] + b1 )
// Gathers are 1KB-coalesced rows of Ybf (bf16, 1 MB/batch -> L2-resident per
// XCD with affinity). Depth-4 upfront loads, named structs (rule #20).
// ---------------------------------------------------------------------------
struct Y4 { short8 y0, y1, y2, s; };

__global__ __launch_bounds__(256) void combine_kernel(
    const ushort* __restrict__ Ybf, const ushort* __restrict__ S,
    const int4* __restrict__ idx3, const float4* __restrict__ w3,
    const float* __restrict__ b1, ushort* __restrict__ h2)
{
  const int xcd  = blockIdx.x & 7;
  const int j    = blockIdx.x >> 3;                  // 0..511 within xcd
  const int widx = j * 4 + (threadIdx.x >> 6);       // 0..2047 within xcd
  const int lane = threadIdx.x & 63;
  const int rbase = xcd * 8192 + widx * 4;           // 4 consecutive rows/wave

  const float4 bA = *(const float4*)(b1 + lane * 8);
  const float4 bB = *(const float4*)(b1 + lane * 8 + 4);

  int4   ids[4];
  float4 wts[4];
#pragma unroll
  for (int k = 0; k < 4; ++k) { ids[k] = idx3[rbase + k]; wts[k] = w3[rbase + k]; }

  const ushort* Yb = Ybf + (size_t)(rbase >> 12) * 524288;  // batch slice

  Y4 r0, r1, r2, r3;
  auto loadr = [&](int k, Y4& r) {
    r.y0 = *(const short8*)(Yb + (size_t)ids[k].x * 512 + lane * 8);
    r.y1 = *(const short8*)(Yb + (size_t)ids[k].y * 512 + lane * 8);
    r.y2 = *(const short8*)(Yb + (size_t)ids[k].z * 512 + lane * 8);
    r.s  = *(const short8*)(S + (size_t)(rbase + k) * 512 + lane * 8);
  };
  loadr(0, r0); loadr(1, r1); loadr(2, r2); loadr(3, r3);
  __builtin_amdgcn_sched_barrier(0);

  auto comp = [&](int k, const Y4& r) {
    const float4 w = wts[k];
    short8 o;
#pragma unroll
    for (int e = 0; e < 8; ++e) {
      const float be = (e < 4) ? ((const float*)&bA)[e] : ((const float*)&bB)[e - 4];
      float v = w.x * bf2f((ushort)r.y0[e])
              + w.y * bf2f((ushort)r.y1[e])
              + w.z * bf2f((ushort)r.y2[e])
              + bf2f((ushort)r.s[e]) + be;
      v = v > 0.f ? v : 0.f;
      o[e] = (short)f2bf(v);
    }
    *(short8*)(h2 + (size_t)(rbase + k) * 512 + lane * 8) = o;
  };
  comp(0, r0); comp(1, r1); comp(2, r2); comp(3, r3);
}

// ---------------------------------------------------------------------------
// 256x256 8-phase bf16 MFMA GEMM (T1..T5). ACT controls bias+relu.
// ---------------------------------------------------------------------------
template<int K, bool OUT_BF16, bool ACT>
__global__ __launch_bounds__(512, 2) void gemm_bias_relu(
    const ushort* __restrict__ A, const ushort* __restrict__ Bt,
    const float* __restrict__ bias, void* __restrict__ Cout, int M, int N)
{
  constexpr int BM = 256, BN = 256, BK = 64, NT = K / BK;
  __shared__ ushort Asm[2][BM * BK];   // 2 x 32 KB
  __shared__ ushort Bsm[2][BN * BK];   // 2 x 32 KB
  const int tid  = threadIdx.x;
  const int lane = tid & 63;
  const int wave = tid >> 6;

  const int cpx  = gridDim.x >> 3;
  const int wgid = (blockIdx.x & 7) * cpx + (blockIdx.x >> 3);
  const int nbn  = N / BN;
  const int bm   = wgid / nbn;
  const int bn   = wgid - bm * nbn;
  const int row0 = bm * BM, col0 = bn * BN;
  const int wr = wave >> 2, wc = wave & 3;
  const int sbase = wave * 4096 + lane * 16;

  f32x4 acc[8][4] = {};

  auto stageA = [&](int buf, int kt) {
#pragma unroll
    for (int i = 0; i < 4; ++i) {
      const int o = sbase + i * 1024;
      const int r = o >> 7, s = (o & 127) >> 4;
      __builtin_amdgcn_global_load_lds(
          (const __attribute__((address_space(1))) void*)(A + (size_t)(row0 + r) * K + kt * BK + ((s ^ (r & 7)) << 3)),
          (__attribute__((address_space(3))) void*)((char*)&Asm[buf][0] + o), 16, 0, 0);
    }
  };
  auto stageB = [&](int buf, int kt) {
#pragma unroll
    for (int i = 0; i < 4; ++i) {
      const int o = sbase + i * 1024;
      const int r = o >> 7, s = (o & 127) >> 4;
      __builtin_amdgcn_global_load_lds(
          (const __attribute__((address_space(1))) void*)(Bt + (size_t)(col0 + r) * K + kt * BK + ((s ^ (r & 7)) << 3)),
          (__attribute__((address_space(3))) void*)((char*)&Bsm[buf][0] + o), 16, 0, 0);
    }
  };
  auto rdA = [&](int buf, int mi, int kk) -> short8 {
    const int ra = wr * 128 + mi * 16 + (lane & 15);
    const int s  = kk * 4 + (lane >> 4);
    return *(const short8*)((const char*)&Asm[buf][0] + ra * 128 + ((s ^ (ra & 7)) << 4));
  };
  auto rdB = [&](int buf, int ni, int kk) -> short8 {
    const int rb = wc * 64 + ni * 16 + (lane & 15);
    const int s  = kk * 4 + (lane >> 4);
    return *(const short8*)((const char*)&Bsm[buf][0] + rb * 128 + ((s ^ (rb & 7)) << 4));
  };

  stageA(0, 0); stageB(0, 0);
  asm volatile("s_waitcnt vmcnt(0)" ::: "memory");
  __builtin_amdgcn_s_barrier();

  int cur = 0;
#pragma unroll 1
  for (int t = 0; t < NT; ++t) {
    short8 av[4], bv[4];
    // phase 0: kk=0, mi 0..3 (+ stage A of t+1)
#pragma unroll
    for (int mi = 0; mi < 4; ++mi) av[mi] = rdA(cur, mi, 0);
#pragma unroll
    for (int ni = 0; ni < 4; ++ni) bv[ni] = rdB(cur, ni, 0);
    if (t + 1 < NT) stageA(cur ^ 1, t + 1);
    __builtin_amdgcn_s_barrier();
    asm volatile("s_waitcnt lgkmcnt(0)" ::: "memory");
    __builtin_amdgcn_sched_barrier(0);
    __builtin_amdgcn_s_setprio(1);
#pragma unroll
    for (int mi = 0; mi < 4; ++mi)
#pragma unroll
      for (int ni = 0; ni < 4; ++ni)
        acc[mi][ni] = __builtin_amdgcn_mfma_f32_16x16x32_bf16(av[mi], bv[ni], acc[mi][ni], 0, 0, 0);
    __builtin_amdgcn_s_setprio(0);
    __builtin_amdgcn_s_barrier();
    // phase 1: kk=0, mi 4..7 (+ stage B of t+1)
#pragma unroll
    for (int mi = 0; mi < 4; ++mi) av[mi] = rdA(cur, 4 + mi, 0);
    if (t + 1 < NT) stageB(cur ^ 1, t + 1);
    __builtin_amdgcn_s_barrier();
    asm volatile("s_waitcnt lgkmcnt(0)" ::: "memory");
    __builtin_amdgcn_sched_barrier(0);
    __builtin_amdgcn_s_setprio(1);
#pragma unroll
    for (int mi = 0; mi < 4; ++mi)
#pragma unroll
      for (int ni = 0; ni < 4; ++ni)
        acc[4 + mi][ni] = __builtin_amdgcn_mfma_f32_16x16x32_bf16(av[mi], bv[ni], acc[4 + mi][ni], 0, 0, 0);
    __builtin_amdgcn_s_setprio(0);
    __builtin_amdgcn_s_barrier();
    // phase 2: kk=1, mi 0..3
#pragma unroll
    for (int mi = 0; mi < 4; ++mi) av[mi] = rdA(cur, mi, 1);
#pragma unroll
    for (int ni = 0; ni < 4; ++ni) bv[ni] = rdB(cur, ni, 1);
    __builtin_amdgcn_s_barrier();
    asm volatile("s_waitcnt lgkmcnt(0)" ::: "memory");
    __builtin_amdgcn_sched_barrier(0);
    __builtin_amdgcn_s_setprio(1);
#pragma unroll
    for (int mi = 0; mi < 4; ++mi)
#pragma unroll
      for (int ni = 0; ni < 4; ++ni)
        acc[mi][ni] = __builtin_amdgcn_mfma_f32_16x16x32_bf16(av[mi], bv[ni], acc[mi][ni], 0, 0, 0);
    __builtin_amdgcn_s_setprio(0);
    __builtin_amdgcn_s_barrier();
    // phase 3: kk=1, mi 4..7 (+ vmcnt drain for t+1)
#pragma unroll
    for (int mi = 0; mi < 4; ++mi) av[mi] = rdA(cur, 4 + mi, 1);
    __builtin_amdgcn_s_barrier();
    asm volatile("s_waitcnt lgkmcnt(0)" ::: "memory");
    __builtin_amdgcn_sched_barrier(0);
    __builtin_amdgcn_s_setprio(1);
#pragma unroll
    for (int mi = 0; mi < 4; ++mi)
#pragma unroll
      for (int ni = 0; ni < 4; ++ni)
        acc[4 + mi][ni] = __builtin_amdgcn_mfma_f32_16x16x32_bf16(av[mi], bv[ni], acc[4 + mi][ni], 0, 0, 0);
    __builtin_amdgcn_s_setprio(0);
    asm volatile("s_waitcnt vmcnt(0)" ::: "memory");
    __builtin_amdgcn_s_barrier();
    cur ^= 1;
  }

  const int lc = lane & 15, lr = lane >> 4;
#pragma unroll
  for (int mi = 0; mi < 8; ++mi) {
#pragma unroll
    for (int ni = 0; ni < 4; ++ni) {
      const int col = col0 + wc * 64 + ni * 16 + lc;
      float bv2 = 0.f;
      if constexpr (ACT) bv2 = bias[col];
      const int rbase = row0 + wr * 128 + mi * 16 + lr * 4;
#pragma unroll
      for (int r = 0; r < 4; ++r) {
        float v = acc[mi][ni][r];
        if constexpr (ACT) { v += bv2; v = v > 0.f ? v : 0.f; }
        if (OUT_BF16) ((ushort*)Cout)[(size_t)(rbase + r) * N + col] = f2bf(v);
        else          ((float*)Cout)[(size_t)(rbase + r) * N + col] = v;
      }
    }
  }
}

// ---------------------------------------------------------------------------
extern "C" void kernel_launch(void* const* d_in, const int* in_sizes, int n_in,
                              void* d_out, int out_size, void* d_ws, size_t ws_size,
                              hipStream_t stream) {
  const float* x        = (const float*)d_in[0];   // [16384, 512]
  const float* pos      = (const float*)d_in[1];   // [16384, 3]
  const float* x_skip   = (const float*)d_in[3];   // [65536, 256]
  const float* pos_skip = (const float*)d_in[4];   // [65536, 3]
  const float* W1       = (const float*)d_in[6];   // [768, 512]
  const float* b1       = (const float*)d_in[7];   // [512]
  const float* W2       = (const float*)d_in[8];   // [512, 512]
  const float* b2       = (const float*)d_in[9];   // [512]

  // d_out (134,217,728 B) as scratch — exact-fit layout, all consumed before
  // GEMM2 overwrites d_out with the final f32 output:
  ushort* Ybf  = (ushort*)d_out;                        // [16384][512]  16.8 MB
  ushort* S    = (ushort*)((char*)d_out + 16777216);    // [65536][512]  67.1 MB
  ushort* xbf  = (ushort*)((char*)d_out + 83886080);    // [16384][512]  16.8 MB
  ushort* xsbf = (ushort*)((char*)d_out + 100663296);   // [65536][256]  33.5 MB

  char* ws = (char*)d_ws;
  ushort* h2   = (ushort*)ws;                          // [65536][512] bf16, 67108864 B
  ushort* W1at = (ushort*)(ws + 67108864);             // [512][512] bf16, 524288 B
  ushort* W1bt = (ushort*)(ws + 67633152);             // [512][256] bf16, 262144 B
  ushort* W2t  = (ushort*)(ws + 67895296);             // [512][512] bf16, 524288 B
  int4*   idx3 = (int4*)  (ws + 68419584);             // [65536] int4, 1 MB
  float4* w3   = (float4*)(ws + 69468160);             // [65536] float4, 1 MB

  // KNN (blocks 0..1023) overlapped with all f32->bf16 converts
  prep_kernel<<<9728, 256, 0, stream>>>(pos, pos_skip, x, x_skip, W1, W2,
                                        idx3, w3, xbf, xsbf, W1at, W1bt, W2t);
  // Y = x @ W1[:512]  (coarse rows only: 16384 x 512, K=512)
  gemm_bias_relu<512, true, false><<<128, 512, 0, stream>>>(xbf, W1at, nullptr, (void*)Ybf, 16384, 512);
  // S = x_skip @ W1[512:768]  (65536 x 512, K=256)
  gemm_bias_relu<256, true, false><<<512, 512, 0, stream>>>(xsbf, W1bt, nullptr, (void*)S, 65536, 512);
  // h2 = relu(gather-combine(Y) + S + b1)
  combine_kernel<<<4096, 256, 0, stream>>>(Ybf, S, idx3, w3, b1, h2);
  // out = relu(h2 @ W2 + b2), f32
  gemm_bias_relu<512, false, true><<<512, 512, 0, stream>>>(h2, W2t, b2, d_out, 65536, 512);
}

// Round 12
// 188.157 us; speedup vs baseline: 1.3587x; 1.0874x over previous
//
#include <hip/hip_runtime.h>
#include <stdint.h>

typedef __attribute__((ext_vector_type(8))) short short8;
typedef __attribute__((ext_vector_type(4))) float f32x4;

static __device__ __forceinline__ ushort f2bf(float f) {
  uint32_t u = __float_as_uint(f);
  uint32_t r = (u + 0x7FFFu + ((u >> 16) & 1u)) >> 16;
  return (ushort)r;
}
static __device__ __forceinline__ float bf2f(ushort h) {
  return __uint_as_float(((uint32_t)h) << 16);
}

// Branchless top-3 insert, f64 (used only in the 4-candidate refine).
static __device__ __forceinline__ void ins3b(double d, int i,
    double& b0, double& b1, double& b2, int& i0, int& i1, int& i2) {
  const bool c0 = d < b0, c1 = d < b1, c2 = d < b2;
  const double nb0 = c0 ? d : b0;
  const int    ni0 = c0 ? i : i0;
  const double nb1 = c0 ? b0 : (c1 ? d : b1);
  const int    ni1 = c0 ? i0 : (c1 ? i : i1);
  const double nb2 = c1 ? b1 : (c2 ? d : b2);
  const int    ni2 = c1 ? i1 : (c2 ? i : i2);
  b0 = nb0; b1 = nb1; b2 = nb2; i0 = ni0; i1 = ni1; i2 = ni2;
}

// ---------------------------------------------------------------------------
// prep: blocks 0..1023 = KNN; 1024..3071 = x f32->bf16;
//       3072..7167 = x_skip f32->bf16; 7168..9727 = weight converts.
// KNN: f32 top-4 scan (cheap select network) + butterfly merge + f64 refine
// of the 4 survivors -> selection matches full-f64 w.p. ~1-1e-9/point.
// ---------------------------------------------------------------------------
__global__ __launch_bounds__(256) void prep_kernel(
    const float* __restrict__ pos, const float* __restrict__ pos_skip,
    const float* __restrict__ x, const float* __restrict__ xs,
    const float* __restrict__ W1, const float* __restrict__ W2,
    int4* __restrict__ idx_out, float4* __restrict__ w_out,
    ushort* __restrict__ xbf, ushort* __restrict__ xsbf,
    ushort* __restrict__ W1at, ushort* __restrict__ W1bt,
    ushort* __restrict__ W2t)
{
  __shared__ float pc[3072];
  if (blockIdx.x < 1024) {
    const int b   = blockIdx.x >> 6;      // 64 blocks per batch
    const int blk = blockIdx.x & 63;      // 64 fine points per block
    for (int j = threadIdx.x; j < 3072; j += 256) pc[j] = pos[b * 3072 + j];
    __syncthreads();

    const int p   = threadIdx.x >> 2;
    const int sub = threadIdx.x & 3;
    const int row = b * 4096 + blk * 64 + p;
    const float pxf = pos_skip[(size_t)row * 3 + 0];
    const float pyf = pos_skip[(size_t)row * 3 + 1];
    const float pzf = pos_skip[(size_t)row * 3 + 2];

    // f32 top-4 scan (select network: 4 cmp + 8 f32 sel + 4 int sel per iter)
    float c0 = 1e30f, c1 = 1e30f, c2 = 1e30f, c3 = 1e30f;
    int   j0 = 0, j1 = 0, j2 = 0, j3 = 0;
    auto ins4 = [&](float d, int i) {
      const bool l0 = d < c0, l1 = d < c1, l2 = d < c2, l3 = d < c3;
      const float n0 = l0 ? d  : c0;              const int m0 = l0 ? i  : j0;
      const float n1 = l0 ? c0 : (l1 ? d : c1);   const int m1 = l0 ? j0 : (l1 ? i : j1);
      const float n2 = l1 ? c1 : (l2 ? d : c2);   const int m2 = l1 ? j1 : (l2 ? i : j2);
      const float n3 = l2 ? c2 : (l3 ? d : c3);   const int m3 = l2 ? j2 : (l3 ? i : j3);
      c0 = n0; c1 = n1; c2 = n2; c3 = n3; j0 = m0; j1 = m1; j2 = m2; j3 = m3;
    };
#pragma unroll 4
    for (int j = 0; j < 256; ++j) {
      const int i = j * 4 + sub;
      const float dx = pc[i * 3 + 0] - pxf;
      const float dy = pc[i * 3 + 1] - pyf;
      const float dz = pc[i * 3 + 2] - pzf;
      ins4(fmaf(dx, dx, fmaf(dy, dy, dz * dz)), i);
    }
    // butterfly merge of top-4 lists across the 4 sub-lanes
#pragma unroll
    for (int m = 1; m <= 2; m <<= 1) {
      const float e0 = __shfl_xor(c0, m), e1 = __shfl_xor(c1, m),
                  e2 = __shfl_xor(c2, m), e3 = __shfl_xor(c3, m);
      const int   f0 = __shfl_xor(j0, m), f1 = __shfl_xor(j1, m),
                  f2 = __shfl_xor(j2, m), f3 = __shfl_xor(j3, m);
      ins4(e0, f0); ins4(e1, f1); ins4(e2, f2); ins4(e3, f3);
    }
    if (sub == 0) {
      // f64 refine: exact distances for the 4 survivors, top-3 re-sort
      const double pxd = (double)pxf, pyd = (double)pyf, pzd = (double)pzf;
      auto exd = [&](int i) -> double {
        const double dx = (double)pc[i * 3 + 0] - pxd;
        const double dy = (double)pc[i * 3 + 1] - pyd;
        const double dz = (double)pc[i * 3 + 2] - pzd;
        return dx * dx + dy * dy + dz * dz;
      };
      double b0 = 1e300, b1 = 1e300, b2 = 1e300;
      int i0 = 0, i1 = 0, i2 = 0;
      ins3b(exd(j0), j0, b0, b1, b2, i0, i1, i2);
      ins3b(exd(j1), j1, b0, b1, b2, i0, i1, i2);
      ins3b(exd(j2), j2, b0, b1, b2, i0, i1, i2);
      ins3b(exd(j3), j3, b0, b1, b2, i0, i1, i2);
      const double w0 = 1.0 / (sqrt(b0) + 1e-8);
      const double w1 = 1.0 / (sqrt(b1) + 1e-8);
      const double w2 = 1.0 / (sqrt(b2) + 1e-8);
      const double den = w0 + w1 + w2 + 1e-8;
      idx_out[row] = make_int4(i0, i1, i2, 0);
      w_out[row] = make_float4((float)(w0 / den), (float)(w1 / den), (float)(w2 / den), 0.f);
    }
  } else if (blockIdx.x < 3072) {
    const int id = (blockIdx.x - 1024) * 256 + threadIdx.x;   // x: 2,097,152 f4
#pragma unroll
    for (int it = 0; it < 4; ++it) {
      const int i = id + it * 524288;
      const float4 v = *(const float4*)(x + (size_t)i * 4);
      ushort4 o = { f2bf(v.x), f2bf(v.y), f2bf(v.z), f2bf(v.w) };
      *(ushort4*)(xbf + (size_t)i * 4) = o;
    }
  } else if (blockIdx.x < 7168) {
    const int id = (blockIdx.x - 3072) * 256 + threadIdx.x;   // xs: 4,194,304 f4
#pragma unroll
    for (int it = 0; it < 4; ++it) {
      const int i = id + it * 1048576;
      const float4 v = *(const float4*)(xs + (size_t)i * 4);
      ushort4 o = { f2bf(v.x), f2bf(v.y), f2bf(v.z), f2bf(v.w) };
      *(ushort4*)(xsbf + (size_t)i * 4) = o;
    }
  } else {
    const int id = (blockIdx.x - 7168) * 256 + threadIdx.x;
    if (id < 262144) {                       // W1at[n][k] = W1[k][n], k<512
      const int n = id >> 9, k = id & 511;
      W1at[id] = f2bf(W1[(size_t)k * 512 + n]);
    } else if (id < 393216) {                // W1bt[n][k] = W1[512+k][n], k<256
      const int id2 = id - 262144;
      const int n = id2 >> 8, k = id2 & 255;
      W1bt[id2] = f2bf(W1[(size_t)(512 + k) * 512 + n]);
    } else if (id < 655360) {                // W2t[n][k] = W2[k][n]
      const int id3 = id - 393216;
      const int n = id3 >> 9, k = id3 & 511;
      W2t[id3] = f2bf(W2[(size_t)k * 512 + n]);
    }
  }
}

// ---------------------------------------------------------------------------
// combine: h2[r] = relu( w.x*Y[id.x] + w.y*Y[id.y] + w.z*Y[id.z] + S[r] + b1 )
// ---------------------------------------------------------------------------
struct Y4 { short8 y0, y1, y2, s; };

__global__ __launch_bounds__(256) void combine_kernel(
    const ushort* __restrict__ Ybf, const ushort* __restrict__ S,
    const int4* __restrict__ idx3, const float4* __restrict__ w3,
    const float* __restrict__ b1, ushort* __restrict__ h2)
{
  const int xcd  = blockIdx.x & 7;
  const int j    = blockIdx.x >> 3;                  // 0..511 within xcd
  const int widx = j * 4 + (threadIdx.x >> 6);       // 0..2047 within xcd
  const int lane = threadIdx.x & 63;
  const int rbase = xcd * 8192 + widx * 4;           // 4 consecutive rows/wave

  const float4 bA = *(const float4*)(b1 + lane * 8);
  const float4 bB = *(const float4*)(b1 + lane * 8 + 4);

  int4   ids[4];
  float4 wts[4];
#pragma unroll
  for (int k = 0; k < 4; ++k) { ids[k] = idx3[rbase + k]; wts[k] = w3[rbase + k]; }

  const ushort* Yb = Ybf + (size_t)(rbase >> 12) * 524288;  // batch slice

  Y4 r0, r1, r2, r3;
  auto loadr = [&](int k, Y4& r) {
    r.y0 = *(const short8*)(Yb + (size_t)ids[k].x * 512 + lane * 8);
    r.y1 = *(const short8*)(Yb + (size_t)ids[k].y * 512 + lane * 8);
    r.y2 = *(const short8*)(Yb + (size_t)ids[k].z * 512 + lane * 8);
    r.s  = *(const short8*)(S + (size_t)(rbase + k) * 512 + lane * 8);
  };
  loadr(0, r0); loadr(1, r1); loadr(2, r2); loadr(3, r3);
  __builtin_amdgcn_sched_barrier(0);

  auto comp = [&](int k, const Y4& r) {
    const float4 w = wts[k];
    short8 o;
#pragma unroll
    for (int e = 0; e < 8; ++e) {
      const float be = (e < 4) ? ((const float*)&bA)[e] : ((const float*)&bB)[e - 4];
      float v = w.x * bf2f((ushort)r.y0[e])
              + w.y * bf2f((ushort)r.y1[e])
              + w.z * bf2f((ushort)r.y2[e])
              + bf2f((ushort)r.s[e]) + be;
      v = v > 0.f ? v : 0.f;
      o[e] = (short)f2bf(v);
    }
    *(short8*)(h2 + (size_t)(rbase + k) * 512 + lane * 8) = o;
  };
  comp(0, r0); comp(1, r1); comp(2, r2); comp(3, r3);
}

// ---------------------------------------------------------------------------
// 256x256 8-phase bf16 MFMA GEMM (T1..T5). ACT controls bias+relu.
// ---------------------------------------------------------------------------
template<int K, bool OUT_BF16, bool ACT>
__global__ __launch_bounds__(512, 2) void gemm_bias_relu(
    const ushort* __restrict__ A, const ushort* __restrict__ Bt,
    const float* __restrict__ bias, void* __restrict__ Cout, int M, int N)
{
  constexpr int BM = 256, BN = 256, BK = 64, NT = K / BK;
  __shared__ ushort Asm[2][BM * BK];   // 2 x 32 KB
  __shared__ ushort Bsm[2][BN * BK];   // 2 x 32 KB
  const int tid  = threadIdx.x;
  const int lane = tid & 63;
  const int wave = tid >> 6;

  const int cpx  = gridDim.x >> 3;
  const int wgid = (blockIdx.x & 7) * cpx + (blockIdx.x >> 3);
  const int nbn  = N / BN;
  const int bm   = wgid / nbn;
  const int bn   = wgid - bm * nbn;
  const int row0 = bm * BM, col0 = bn * BN;
  const int wr = wave >> 2, wc = wave & 3;
  const int sbase = wave * 4096 + lane * 16;

  f32x4 acc[8][4] = {};

  auto stageA = [&](int buf, int kt) {
#pragma unroll
    for (int i = 0; i < 4; ++i) {
      const int o = sbase + i * 1024;
      const int r = o >> 7, s = (o & 127) >> 4;
      __builtin_amdgcn_global_load_lds(
          (const __attribute__((address_space(1))) void*)(A + (size_t)(row0 + r) * K + kt * BK + ((s ^ (r & 7)) << 3)),
          (__attribute__((address_space(3))) void*)((char*)&Asm[buf][0] + o), 16, 0, 0);
    }
  };
  auto stageB = [&](int buf, int kt) {
#pragma unroll
    for (int i = 0; i < 4; ++i) {
      const int o = sbase + i * 1024;
      const int r = o >> 7, s = (o & 127) >> 4;
      __builtin_amdgcn_global_load_lds(
          (const __attribute__((address_space(1))) void*)(Bt + (size_t)(col0 + r) * K + kt * BK + ((s ^ (r & 7)) << 3)),
          (__attribute__((address_space(3))) void*)((char*)&Bsm[buf][0] + o), 16, 0, 0);
    }
  };
  auto rdA = [&](int buf, int mi, int kk) -> short8 {
    const int ra = wr * 128 + mi * 16 + (lane & 15);
    const int s  = kk * 4 + (lane >> 4);
    return *(const short8*)((const char*)&Asm[buf][0] + ra * 128 + ((s ^ (ra & 7)) << 4));
  };
  auto rdB = [&](int buf, int ni, int kk) -> short8 {
    const int rb = wc * 64 + ni * 16 + (lane & 15);
    const int s  = kk * 4 + (lane >> 4);
    return *(const short8*)((const char*)&Bsm[buf][0] + rb * 128 + ((s ^ (rb & 7)) << 4));
  };

  stageA(0, 0); stageB(0, 0);
  asm volatile("s_waitcnt vmcnt(0)" ::: "memory");
  __builtin_amdgcn_s_barrier();

  int cur = 0;
#pragma unroll 1
  for (int t = 0; t < NT; ++t) {
    short8 av[4], bv[4];
    // phase 0: kk=0, mi 0..3 (+ stage A of t+1)
#pragma unroll
    for (int mi = 0; mi < 4; ++mi) av[mi] = rdA(cur, mi, 0);
#pragma unroll
    for (int ni = 0; ni < 4; ++ni) bv[ni] = rdB(cur, ni, 0);
    if (t + 1 < NT) stageA(cur ^ 1, t + 1);
    __builtin_amdgcn_s_barrier();
    asm volatile("s_waitcnt lgkmcnt(0)" ::: "memory");
    __builtin_amdgcn_sched_barrier(0);
    __builtin_amdgcn_s_setprio(1);
#pragma unroll
    for (int mi = 0; mi < 4; ++mi)
#pragma unroll
      for (int ni = 0; ni < 4; ++ni)
        acc[mi][ni] = __builtin_amdgcn_mfma_f32_16x16x32_bf16(av[mi], bv[ni], acc[mi][ni], 0, 0, 0);
    __builtin_amdgcn_s_setprio(0);
    __builtin_amdgcn_s_barrier();
    // phase 1: kk=0, mi 4..7 (+ stage B of t+1)
#pragma unroll
    for (int mi = 0; mi < 4; ++mi) av[mi] = rdA(cur, 4 + mi, 0);
    if (t + 1 < NT) stageB(cur ^ 1, t + 1);
    __builtin_amdgcn_s_barrier();
    asm volatile("s_waitcnt lgkmcnt(0)" ::: "memory");
    __builtin_amdgcn_sched_barrier(0);
    __builtin_amdgcn_s_setprio(1);
#pragma unroll
    for (int mi = 0; mi < 4; ++mi)
#pragma unroll
      for (int ni = 0; ni < 4; ++ni)
        acc[4 + mi][ni] = __builtin_amdgcn_mfma_f32_16x16x32_bf16(av[mi], bv[ni], acc[4 + mi][ni], 0, 0, 0);
    __builtin_amdgcn_s_setprio(0);
    __builtin_amdgcn_s_barrier();
    // phase 2: kk=1, mi 0..3
#pragma unroll
    for (int mi = 0; mi < 4; ++mi) av[mi] = rdA(cur, mi, 1);
#pragma unroll
    for (int ni = 0; ni < 4; ++ni) bv[ni] = rdB(cur, ni, 1);
    __builtin_amdgcn_s_barrier();
    asm volatile("s_waitcnt lgkmcnt(0)" ::: "memory");
    __builtin_amdgcn_sched_barrier(0);
    __builtin_amdgcn_s_setprio(1);
#pragma unroll
    for (int mi = 0; mi < 4; ++mi)
#pragma unroll
      for (int ni = 0; ni < 4; ++ni)
        acc[mi][ni] = __builtin_amdgcn_mfma_f32_16x16x32_bf16(av[mi], bv[ni], acc[mi][ni], 0, 0, 0);
    __builtin_amdgcn_s_setprio(0);
    __builtin_amdgcn_s_barrier();
    // phase 3: kk=1, mi 4..7 (+ vmcnt drain for t+1)
#pragma unroll
    for (int mi = 0; mi < 4; ++mi) av[mi] = rdA(cur, 4 + mi, 1);
    __builtin_amdgcn_s_barrier();
    asm volatile("s_waitcnt lgkmcnt(0)" ::: "memory");
    __builtin_amdgcn_sched_barrier(0);
    __builtin_amdgcn_s_setprio(1);
#pragma unroll
    for (int mi = 0; mi < 4; ++mi)
#pragma unroll
      for (int ni = 0; ni < 4; ++ni)
        acc[4 + mi][ni] = __builtin_amdgcn_mfma_f32_16x16x32_bf16(av[mi], bv[ni], acc[4 + mi][ni], 0, 0, 0);
    __builtin_amdgcn_s_setprio(0);
    asm volatile("s_waitcnt vmcnt(0)" ::: "memory");
    __builtin_amdgcn_s_barrier();
    cur ^= 1;
  }

  const int lc = lane & 15, lr = lane >> 4;
#pragma unroll
  for (int mi = 0; mi < 8; ++mi) {
#pragma unroll
    for (int ni = 0; ni < 4; ++ni) {
      const int col = col0 + wc * 64 + ni * 16 + lc;
      float bv2 = 0.f;
      if constexpr (ACT) bv2 = bias[col];
      const int rbase = row0 + wr * 128 + mi * 16 + lr * 4;
#pragma unroll
      for (int r = 0; r < 4; ++r) {
        float v = acc[mi][ni][r];
        if constexpr (ACT) { v += bv2; v = v > 0.f ? v : 0.f; }
        if (OUT_BF16) ((ushort*)Cout)[(size_t)(rbase + r) * N + col] = f2bf(v);
        else          ((float*)Cout)[(size_t)(rbase + r) * N + col] = v;
      }
    }
  }
}

// ---------------------------------------------------------------------------
extern "C" void kernel_launch(void* const* d_in, const int* in_sizes, int n_in,
                              void* d_out, int out_size, void* d_ws, size_t ws_size,
                              hipStream_t stream) {
  const float* x        = (const float*)d_in[0];   // [16384, 512]
  const float* pos      = (const float*)d_in[1];   // [16384, 3]
  const float* x_skip   = (const float*)d_in[3];   // [65536, 256]
  const float* pos_skip = (const float*)d_in[4];   // [65536, 3]
  const float* W1       = (const float*)d_in[6];   // [768, 512]
  const float* b1       = (const float*)d_in[7];   // [512]
  const float* W2       = (const float*)d_in[8];   // [512, 512]
  const float* b2       = (const float*)d_in[9];   // [512]

  // d_out (134,217,728 B) as scratch — exact-fit layout, all consumed before
  // GEMM2 overwrites d_out with the final f32 output:
  ushort* Ybf  = (ushort*)d_out;                        // [16384][512]  16.8 MB
  ushort* S    = (ushort*)((char*)d_out + 16777216);    // [65536][512]  67.1 MB
  ushort* xbf  = (ushort*)((char*)d_out + 83886080);    // [16384][512]  16.8 MB
  ushort* xsbf = (ushort*)((char*)d_out + 100663296);   // [65536][256]  33.5 MB

  char* ws = (char*)d_ws;
  ushort* h2   = (ushort*)ws;                          // [65536][512] bf16, 67108864 B
  ushort* W1at = (ushort*)(ws + 67108864);             // [512][512] bf16, 524288 B
  ushort* W1bt = (ushort*)(ws + 67633152);             // [512][256] bf16, 262144 B
  ushort* W2t  = (ushort*)(ws + 67895296);             // [512][512] bf16, 524288 B
  int4*   idx3 = (int4*)  (ws + 68419584);             // [65536] int4, 1 MB
  float4* w3   = (float4*)(ws + 69468160);             // [65536] float4, 1 MB

  // KNN (blocks 0..1023) overlapped with all f32->bf16 converts
  prep_kernel<<<9728, 256, 0, stream>>>(pos, pos_skip, x, x_skip, W1, W2,
                                        idx3, w3, xbf, xsbf, W1at, W1bt, W2t);
  // Y = x @ W1[:512]  (coarse rows only: 16384 x 512, K=512)
  gemm_bias_relu<512, true, false><<<128, 512, 0, stream>>>(xbf, W1at, nullptr, (void*)Ybf, 16384, 512);
  // S = x_skip @ W1[512:768]  (65536 x 512, K=256)
  gemm_bias_relu<256, true, false><<<512, 512, 0, stream>>>(xsbf, W1bt, nullptr, (void*)S, 65536, 512);
  // h2 = relu(gather-combine(Y) + S + b1)
  combine_kernel<<<4096, 256, 0, stream>>>(Ybf, S, idx3, w3, b1, h2);
  // out = relu(h2 @ W2 + b2), f32
  gemm_bias_relu<512, false, true><<<512, 512, 0, stream>>>(h2, W2t, b2, d_out, 65536, 512);
}

// Round 13
// 174.072 us; speedup vs baseline: 1.4687x; 1.0809x over previous
//
#include <hip/hip_runtime.h>
#include <stdint.h>

typedef __attribute__((ext_vector_type(8))) short short8;
typedef __attribute__((ext_vector_type(4))) float f32x4;

static __device__ __forceinline__ ushort f2bf(float f) {
  uint32_t u = __float_as_uint(f);
  uint32_t r = (u + 0x7FFFu + ((u >> 16) & 1u)) >> 16;
  return (ushort)r;
}
static __device__ __forceinline__ float bf2f(ushort h) {
  return __uint_as_float(((uint32_t)h) << 16);
}

// Branchless top-3 insert, f64 (used only in the 4-candidate refine).
static __device__ __forceinline__ void ins3b(double d, int i,
    double& b0, double& b1, double& b2, int& i0, int& i1, int& i2) {
  const bool c0 = d < b0, c1 = d < b1, c2 = d < b2;
  const double nb0 = c0 ? d : b0;
  const int    ni0 = c0 ? i : i0;
  const double nb1 = c0 ? b0 : (c1 ? d : b1);
  const int    ni1 = c0 ? i0 : (c1 ? i : i1);
  const double nb2 = c1 ? b1 : (c2 ? d : b2);
  const int    ni2 = c1 ? i1 : (c2 ? i : i2);
  b0 = nb0; b1 = nb1; b2 = nb2; i0 = ni0; i1 = ni1; i2 = ni2;
}

// ---------------------------------------------------------------------------
// prep: blocks 0..1023 = KNN; 1024..3071 = x f32->bf16;
//       3072..7167 = x_skip f32->bf16; 7168..9727 = weight converts.
// KNN: packed-key u32 top-4 scan (key = d2-bits & ~1023 | idx; f32 order ==
// u32 order for d>=0; idx rides in the low 10 bits so the select network is
// 4 cmp + 4 cndmask, no index selects) + butterfly merge + f64 refine of the
// 4 survivors (packing error ~2^-13 rel << 3rd..5th gaps -> exact selection).
// ---------------------------------------------------------------------------
__global__ __launch_bounds__(256) void prep_kernel(
    const float* __restrict__ pos, const float* __restrict__ pos_skip,
    const float* __restrict__ x, const float* __restrict__ xs,
    const float* __restrict__ W1, const float* __restrict__ W2,
    int4* __restrict__ idx_out, float4* __restrict__ w_out,
    ushort* __restrict__ xbf, ushort* __restrict__ xsbf,
    ushort* __restrict__ W1at, ushort* __restrict__ W1bt,
    ushort* __restrict__ W2t)
{
  __shared__ float pc4[4096];          // [1024][4] padded coarse positions
  if (blockIdx.x < 1024) {
    const int b   = blockIdx.x >> 6;      // 64 blocks per batch
    const int blk = blockIdx.x & 63;      // 64 fine points per block
    for (int i = threadIdx.x; i < 1024; i += 256) {
      const float* ps = pos + (size_t)b * 3072 + i * 3;
      float4 v = { ps[0], ps[1], ps[2], 0.f };
      *(float4*)&pc4[i * 4] = v;
    }
    __syncthreads();

    const int p   = threadIdx.x >> 2;
    const int sub = threadIdx.x & 3;
    const int row = b * 4096 + blk * 64 + p;
    const float pxf = pos_skip[(size_t)row * 3 + 0];
    const float pyf = pos_skip[(size_t)row * 3 + 1];
    const float pzf = pos_skip[(size_t)row * 3 + 2];

    uint32_t c0 = 0xFFFFFFFFu, c1 = 0xFFFFFFFFu, c2 = 0xFFFFFFFFu, c3 = 0xFFFFFFFFu;
    auto ins4u = [&](uint32_t k) {
      const bool l0 = k < c0, l1 = k < c1, l2 = k < c2, l3 = k < c3;
      const uint32_t n0 = l0 ? k  : c0;
      const uint32_t n1 = l0 ? c0 : (l1 ? k : c1);
      const uint32_t n2 = l1 ? c1 : (l2 ? k : c2);
      const uint32_t n3 = l2 ? c2 : (l3 ? k : c3);
      c0 = n0; c1 = n1; c2 = n2; c3 = n3;
    };
#pragma unroll 4
    for (int j = 0; j < 256; ++j) {
      const int i = j * 4 + sub;
      const float4 q = *(const float4*)&pc4[i * 4];
      const float dx = q.x - pxf;
      const float dy = q.y - pyf;
      const float dz = q.z - pzf;
      const float d = fmaf(dx, dx, fmaf(dy, dy, dz * dz));
      ins4u((__float_as_uint(d) & 0xFFFFFC00u) | (uint32_t)i);
    }
    // butterfly merge of top-4 key lists across the 4 sub-lanes
#pragma unroll
    for (int m = 1; m <= 2; m <<= 1) {
      const uint32_t e0 = (uint32_t)__shfl_xor((int)c0, m);
      const uint32_t e1 = (uint32_t)__shfl_xor((int)c1, m);
      const uint32_t e2 = (uint32_t)__shfl_xor((int)c2, m);
      const uint32_t e3 = (uint32_t)__shfl_xor((int)c3, m);
      ins4u(e0); ins4u(e1); ins4u(e2); ins4u(e3);
    }
    if (sub == 0) {
      // f64 refine: exact distances for the 4 survivors, top-3 re-sort
      const double pxd = (double)pxf, pyd = (double)pyf, pzd = (double)pzf;
      auto exd = [&](int i) -> double {
        const double dx = (double)pc4[i * 4 + 0] - pxd;
        const double dy = (double)pc4[i * 4 + 1] - pyd;
        const double dz = (double)pc4[i * 4 + 2] - pzd;
        return dx * dx + dy * dy + dz * dz;
      };
      const int j0 = (int)(c0 & 1023u), j1 = (int)(c1 & 1023u);
      const int j2 = (int)(c2 & 1023u), j3 = (int)(c3 & 1023u);
      double b0 = 1e300, b1 = 1e300, b2 = 1e300;
      int i0 = 0, i1 = 0, i2 = 0;
      ins3b(exd(j0), j0, b0, b1, b2, i0, i1, i2);
      ins3b(exd(j1), j1, b0, b1, b2, i0, i1, i2);
      ins3b(exd(j2), j2, b0, b1, b2, i0, i1, i2);
      ins3b(exd(j3), j3, b0, b1, b2, i0, i1, i2);
      const double w0 = 1.0 / (sqrt(b0) + 1e-8);
      const double w1 = 1.0 / (sqrt(b1) + 1e-8);
      const double w2 = 1.0 / (sqrt(b2) + 1e-8);
      const double den = w0 + w1 + w2 + 1e-8;
      idx_out[row] = make_int4(i0, i1, i2, 0);
      w_out[row] = make_float4((float)(w0 / den), (float)(w1 / den), (float)(w2 / den), 0.f);
    }
  } else if (blockIdx.x < 3072) {
    const int id = (blockIdx.x - 1024) * 256 + threadIdx.x;   // x: 2,097,152 f4
#pragma unroll
    for (int it = 0; it < 4; ++it) {
      const int i = id + it * 524288;
      const float4 v = *(const float4*)(x + (size_t)i * 4);
      ushort4 o = { f2bf(v.x), f2bf(v.y), f2bf(v.z), f2bf(v.w) };
      *(ushort4*)(xbf + (size_t)i * 4) = o;
    }
  } else if (blockIdx.x < 7168) {
    const int id = (blockIdx.x - 3072) * 256 + threadIdx.x;   // xs: 4,194,304 f4
#pragma unroll
    for (int it = 0; it < 4; ++it) {
      const int i = id + it * 1048576;
      const float4 v = *(const float4*)(xs + (size_t)i * 4);
      ushort4 o = { f2bf(v.x), f2bf(v.y), f2bf(v.z), f2bf(v.w) };
      *(ushort4*)(xsbf + (size_t)i * 4) = o;
    }
  } else {
    const int id = (blockIdx.x - 7168) * 256 + threadIdx.x;
    if (id < 262144) {                       // W1at[n][k] = W1[k][n], k<512
      const int n = id >> 9, k = id & 511;
      W1at[id] = f2bf(W1[(size_t)k * 512 + n]);
    } else if (id < 393216) {                // W1bt[n][k] = W1[512+k][n], k<256
      const int id2 = id - 262144;
      const int n = id2 >> 8, k = id2 & 255;
      W1bt[id2] = f2bf(W1[(size_t)(512 + k) * 512 + n]);
    } else if (id < 655360) {                // W2t[n][k] = W2[k][n]
      const int id3 = id - 393216;
      const int n = id3 >> 9, k = id3 & 511;
      W2t[id3] = f2bf(W2[(size_t)k * 512 + n]);
    }
  }
}

// ---------------------------------------------------------------------------
// combine: h2[r] = relu( w.x*Y[id.x] + w.y*Y[id.y] + w.z*Y[id.z] + S[r] + b1 )
// ---------------------------------------------------------------------------
struct Y4 { short8 y0, y1, y2, s; };

__global__ __launch_bounds__(256) void combine_kernel(
    const ushort* __restrict__ Ybf, const ushort* __restrict__ S,
    const int4* __restrict__ idx3, const float4* __restrict__ w3,
    const float* __restrict__ b1, ushort* __restrict__ h2)
{
  const int xcd  = blockIdx.x & 7;
  const int j    = blockIdx.x >> 3;                  // 0..511 within xcd
  const int widx = j * 4 + (threadIdx.x >> 6);       // 0..2047 within xcd
  const int lane = threadIdx.x & 63;
  const int rbase = xcd * 8192 + widx * 4;           // 4 consecutive rows/wave

  const float4 bA = *(const float4*)(b1 + lane * 8);
  const float4 bB = *(const float4*)(b1 + lane * 8 + 4);

  int4   ids[4];
  float4 wts[4];
#pragma unroll
  for (int k = 0; k < 4; ++k) { ids[k] = idx3[rbase + k]; wts[k] = w3[rbase + k]; }

  const ushort* Yb = Ybf + (size_t)(rbase >> 12) * 524288;  // batch slice

  Y4 r0, r1, r2, r3;
  auto loadr = [&](int k, Y4& r) {
    r.y0 = *(const short8*)(Yb + (size_t)ids[k].x * 512 + lane * 8);
    r.y1 = *(const short8*)(Yb + (size_t)ids[k].y * 512 + lane * 8);
    r.y2 = *(const short8*)(Yb + (size_t)ids[k].z * 512 + lane * 8);
    r.s  = *(const short8*)(S + (size_t)(rbase + k) * 512 + lane * 8);
  };
  loadr(0, r0); loadr(1, r1); loadr(2, r2); loadr(3, r3);
  __builtin_amdgcn_sched_barrier(0);

  auto comp = [&](int k, const Y4& r) {
    const float4 w = wts[k];
    short8 o;
#pragma unroll
    for (int e = 0; e < 8; ++e) {
      const float be = (e < 4) ? ((const float*)&bA)[e] : ((const float*)&bB)[e - 4];
      float v = w.x * bf2f((ushort)r.y0[e])
              + w.y * bf2f((ushort)r.y1[e])
              + w.z * bf2f((ushort)r.y2[e])
              + bf2f((ushort)r.s[e]) + be;
      v = v > 0.f ? v : 0.f;
      o[e] = (short)f2bf(v);
    }
    *(short8*)(h2 + (size_t)(rbase + k) * 512 + lane * 8) = o;
  };
  comp(0, r0); comp(1, r1); comp(2, r2); comp(3, r3);
}

// ---------------------------------------------------------------------------
// 256x256 8-phase bf16 MFMA GEMM (T1..T5). ACT controls bias+relu.
// ---------------------------------------------------------------------------
template<int K, bool OUT_BF16, bool ACT>
__global__ __launch_bounds__(512, 2) void gemm_bias_relu(
    const ushort* __restrict__ A, const ushort* __restrict__ Bt,
    const float* __restrict__ bias, void* __restrict__ Cout, int M, int N)
{
  constexpr int BM = 256, BN = 256, BK = 64, NT = K / BK;
  __shared__ ushort Asm[2][BM * BK];   // 2 x 32 KB
  __shared__ ushort Bsm[2][BN * BK];   // 2 x 32 KB
  const int tid  = threadIdx.x;
  const int lane = tid & 63;
  const int wave = tid >> 6;

  const int cpx  = gridDim.x >> 3;
  const int wgid = (blockIdx.x & 7) * cpx + (blockIdx.x >> 3);
  const int nbn  = N / BN;
  const int bm   = wgid / nbn;
  const int bn   = wgid - bm * nbn;
  const int row0 = bm * BM, col0 = bn * BN;
  const int wr = wave >> 2, wc = wave & 3;
  const int sbase = wave * 4096 + lane * 16;

  f32x4 acc[8][4] = {};

  auto stageA = [&](int buf, int kt) {
#pragma unroll
    for (int i = 0; i < 4; ++i) {
      const int o = sbase + i * 1024;
      const int r = o >> 7, s = (o & 127) >> 4;
      __builtin_amdgcn_global_load_lds(
          (const __attribute__((address_space(1))) void*)(A + (size_t)(row0 + r) * K + kt * BK + ((s ^ (r & 7)) << 3)),
          (__attribute__((address_space(3))) void*)((char*)&Asm[buf][0] + o), 16, 0, 0);
    }
  };
  auto stageB = [&](int buf, int kt) {
#pragma unroll
    for (int i = 0; i < 4; ++i) {
      const int o = sbase + i * 1024;
      const int r = o >> 7, s = (o & 127) >> 4;
      __builtin_amdgcn_global_load_lds(
          (const __attribute__((address_space(1))) void*)(Bt + (size_t)(col0 + r) * K + kt * BK + ((s ^ (r & 7)) << 3)),
          (__attribute__((address_space(3))) void*)((char*)&Bsm[buf][0] + o), 16, 0, 0);
    }
  };
  auto rdA = [&](int buf, int mi, int kk) -> short8 {
    const int ra = wr * 128 + mi * 16 + (lane & 15);
    const int s  = kk * 4 + (lane >> 4);
    return *(const short8*)((const char*)&Asm[buf][0] + ra * 128 + ((s ^ (ra & 7)) << 4));
  };
  auto rdB = [&](int buf, int ni, int kk) -> short8 {
    const int rb = wc * 64 + ni * 16 + (lane & 15);
    const int s  = kk * 4 + (lane >> 4);
    return *(const short8*)((const char*)&Bsm[buf][0] + rb * 128 + ((s ^ (rb & 7)) << 4));
  };

  stageA(0, 0); stageB(0, 0);
  asm volatile("s_waitcnt vmcnt(0)" ::: "memory");
  __builtin_amdgcn_s_barrier();

  int cur = 0;
#pragma unroll 1
  for (int t = 0; t < NT; ++t) {
    short8 av[4], bv[4];
    // phase 0: kk=0, mi 0..3 (+ stage A of t+1)
#pragma unroll
    for (int mi = 0; mi < 4; ++mi) av[mi] = rdA(cur, mi, 0);
#pragma unroll
    for (int ni = 0; ni < 4; ++ni) bv[ni] = rdB(cur, ni, 0);
    if (t + 1 < NT) stageA(cur ^ 1, t + 1);
    __builtin_amdgcn_s_barrier();
    asm volatile("s_waitcnt lgkmcnt(0)" ::: "memory");
    __builtin_amdgcn_sched_barrier(0);
    __builtin_amdgcn_s_setprio(1);
#pragma unroll
    for (int mi = 0; mi < 4; ++mi)
#pragma unroll
      for (int ni = 0; ni < 4; ++ni)
        acc[mi][ni] = __builtin_amdgcn_mfma_f32_16x16x32_bf16(av[mi], bv[ni], acc[mi][ni], 0, 0, 0);
    __builtin_amdgcn_s_setprio(0);
    __builtin_amdgcn_s_barrier();
    // phase 1: kk=0, mi 4..7 (+ stage B of t+1)
#pragma unroll
    for (int mi = 0; mi < 4; ++mi) av[mi] = rdA(cur, 4 + mi, 0);
    if (t + 1 < NT) stageB(cur ^ 1, t + 1);
    __builtin_amdgcn_s_barrier();
    asm volatile("s_waitcnt lgkmcnt(0)" ::: "memory");
    __builtin_amdgcn_sched_barrier(0);
    __builtin_amdgcn_s_setprio(1);
#pragma unroll
    for (int mi = 0; mi < 4; ++mi)
#pragma unroll
      for (int ni = 0; ni < 4; ++ni)
        acc[4 + mi][ni] = __builtin_amdgcn_mfma_f32_16x16x32_bf16(av[mi], bv[ni], acc[4 + mi][ni], 0, 0, 0);
    __builtin_amdgcn_s_setprio(0);
    __builtin_amdgcn_s_barrier();
    // phase 2: kk=1, mi 0..3
#pragma unroll
    for (int mi = 0; mi < 4; ++mi) av[mi] = rdA(cur, mi, 1);
#pragma unroll
    for (int ni = 0; ni < 4; ++ni) bv[ni] = rdB(cur, ni, 1);
    __builtin_amdgcn_s_barrier();
    asm volatile("s_waitcnt lgkmcnt(0)" ::: "memory");
    __builtin_amdgcn_sched_barrier(0);
    __builtin_amdgcn_s_setprio(1);
#pragma unroll
    for (int mi = 0; mi < 4; ++mi)
#pragma unroll
      for (int ni = 0; ni < 4; ++ni)
        acc[mi][ni] = __builtin_amdgcn_mfma_f32_16x16x32_bf16(av[mi], bv[ni], acc[mi][ni], 0, 0, 0);
    __builtin_amdgcn_s_setprio(0);
    __builtin_amdgcn_s_barrier();
    // phase 3: kk=1, mi 4..7 (+ vmcnt drain for t+1)
#pragma unroll
    for (int mi = 0; mi < 4; ++mi) av[mi] = rdA(cur, 4 + mi, 1);
    __builtin_amdgcn_s_barrier();
    asm volatile("s_waitcnt lgkmcnt(0)" ::: "memory");
    __builtin_amdgcn_sched_barrier(0);
    __builtin_amdgcn_s_setprio(1);
#pragma unroll
    for (int mi = 0; mi < 4; ++mi)
#pragma unroll
      for (int ni = 0; ni < 4; ++ni)
        acc[4 + mi][ni] = __builtin_amdgcn_mfma_f32_16x16x32_bf16(av[mi], bv[ni], acc[4 + mi][ni], 0, 0, 0);
    __builtin_amdgcn_s_setprio(0);
    asm volatile("s_waitcnt vmcnt(0)" ::: "memory");
    __builtin_amdgcn_s_barrier();
    cur ^= 1;
  }

  const int lc = lane & 15, lr = lane >> 4;
#pragma unroll
  for (int mi = 0; mi < 8; ++mi) {
#pragma unroll
    for (int ni = 0; ni < 4; ++ni) {
      const int col = col0 + wc * 64 + ni * 16 + lc;
      float bv2 = 0.f;
      if constexpr (ACT) bv2 = bias[col];
      const int rbase = row0 + wr * 128 + mi * 16 + lr * 4;
#pragma unroll
      for (int r = 0; r < 4; ++r) {
        float v = acc[mi][ni][r];
        if constexpr (ACT) { v += bv2; v = v > 0.f ? v : 0.f; }
        if (OUT_BF16) ((ushort*)Cout)[(size_t)(rbase + r) * N + col] = f2bf(v);
        else          ((float*)Cout)[(size_t)(rbase + r) * N + col] = v;
      }
    }
  }
}

// ---------------------------------------------------------------------------
extern "C" void kernel_launch(void* const* d_in, const int* in_sizes, int n_in,
                              void* d_out, int out_size, void* d_ws, size_t ws_size,
                              hipStream_t stream) {
  const float* x        = (const float*)d_in[0];   // [16384, 512]
  const float* pos      = (const float*)d_in[1];   // [16384, 3]
  const float* x_skip   = (const float*)d_in[3];   // [65536, 256]
  const float* pos_skip = (const float*)d_in[4];   // [65536, 3]
  const float* W1       = (const float*)d_in[6];   // [768, 512]
  const float* b1       = (const float*)d_in[7];   // [512]
  const float* W2       = (const float*)d_in[8];   // [512, 512]
  const float* b2       = (const float*)d_in[9];   // [512]

  // d_out (134,217,728 B) as scratch — exact-fit layout, all consumed before
  // GEMM2 overwrites d_out with the final f32 output:
  ushort* Ybf  = (ushort*)d_out;                        // [16384][512]  16.8 MB
  ushort* S    = (ushort*)((char*)d_out + 16777216);    // [65536][512]  67.1 MB
  ushort* xbf  = (ushort*)((char*)d_out + 83886080);    // [16384][512]  16.8 MB
  ushort* xsbf = (ushort*)((char*)d_out + 100663296);   // [65536][256]  33.5 MB

  char* ws = (char*)d_ws;
  ushort* h2   = (ushort*)ws;                          // [65536][512] bf16, 67108864 B
  ushort* W1at = (ushort*)(ws + 67108864);             // [512][512] bf16, 524288 B
  ushort* W1bt = (ushort*)(ws + 67633152);             // [512][256] bf16, 262144 B
  ushort* W2t  = (ushort*)(ws + 67895296);             // [512][512] bf16, 524288 B
  int4*   idx3 = (int4*)  (ws + 68419584);             // [65536] int4, 1 MB
  float4* w3   = (float4*)(ws + 69468160);             // [65536] float4, 1 MB

  // KNN (blocks 0..1023) overlapped with all f32->bf16 converts
  prep_kernel<<<9728, 256, 0, stream>>>(pos, pos_skip, x, x_skip, W1, W2,
                                        idx3, w3, xbf, xsbf, W1at, W1bt, W2t);
  // Y = x @ W1[:512]  (coarse rows only: 16384 x 512, K=512)
  gemm_bias_relu<512, true, false><<<128, 512, 0, stream>>>(xbf, W1at, nullptr, (void*)Ybf, 16384, 512);
  // S = x_skip @ W1[512:768]  (65536 x 512, K=256)
  gemm_bias_relu<256, true, false><<<512, 512, 0, stream>>>(xsbf, W1bt, nullptr, (void*)S, 65536, 512);
  // h2 = relu(gather-combine(Y) + S + b1)
  combine_kernel<<<4096, 256, 0, stream>>>(Ybf, S, idx3, w3, b1, h2);
  // out = relu(h2 @ W2 + b2), f32
  gemm_bias_relu<512, false, true><<<512, 512, 0, stream>>>(h2, W2t, b2, d_out, 65536, 512);
}

// Round 14
// 169.277 us; speedup vs baseline: 1.5103x; 1.0283x over previous
//
#include <hip/hip_runtime.h>
#include <stdint.h>

typedef __attribute__((ext_vector_type(8))) short short8;
typedef __attribute__((ext_vector_type(4))) float f32x4;

static __device__ __forceinline__ ushort f2bf(float f) {
  uint32_t u = __float_as_uint(f);
  uint32_t r = (u + 0x7FFFu + ((u >> 16) & 1u)) >> 16;
  return (ushort)r;
}
static __device__ __forceinline__ float bf2f(ushort h) {
  return __uint_as_float(((uint32_t)h) << 16);
}

// Branchless top-3 insert, f64 (used only in the 4-candidate refine).
static __device__ __forceinline__ void ins3b(double d, int i,
    double& b0, double& b1, double& b2, int& i0, int& i1, int& i2) {
  const bool c0 = d < b0, c1 = d < b1, c2 = d < b2;
  const double nb0 = c0 ? d : b0;
  const int    ni0 = c0 ? i : i0;
  const double nb1 = c0 ? b0 : (c1 ? d : b1);
  const int    ni1 = c0 ? i0 : (c1 ? i : i1);
  const double nb2 = c1 ? b1 : (c2 ? d : b2);
  const int    ni2 = c1 ? i1 : (c2 ? i : i2);
  b0 = nb0; b1 = nb1; b2 = nb2; i0 = ni0; i1 = ni1; i2 = ni2;
}

// ---------------------------------------------------------------------------
// prep: blocks 0..1023 = KNN (packed-key u32 top-4 + f64 refine);
//       1024..3071 = x f32->bf16; 3072..7167 = x_skip f32->bf16;
//       7168..9727 = weight converts.
// ---------------------------------------------------------------------------
__global__ __launch_bounds__(256) void prep_kernel(
    const float* __restrict__ pos, const float* __restrict__ pos_skip,
    const float* __restrict__ x, const float* __restrict__ xs,
    const float* __restrict__ W1, const float* __restrict__ W2,
    int4* __restrict__ idx_out, float4* __restrict__ w_out,
    ushort* __restrict__ xbf, ushort* __restrict__ xsbf,
    ushort* __restrict__ W1at, ushort* __restrict__ W1bt,
    ushort* __restrict__ W2t)
{
  __shared__ float pc4[4096];          // [1024][4] padded coarse positions
  if (blockIdx.x < 1024) {
    const int b   = blockIdx.x >> 6;      // 64 blocks per batch
    const int blk = blockIdx.x & 63;      // 64 fine points per block
    for (int i = threadIdx.x; i < 1024; i += 256) {
      const float* ps = pos + (size_t)b * 3072 + i * 3;
      float4 v = { ps[0], ps[1], ps[2], 0.f };
      *(float4*)&pc4[i * 4] = v;
    }
    __syncthreads();

    const int p   = threadIdx.x >> 2;
    const int sub = threadIdx.x & 3;
    const int row = b * 4096 + blk * 64 + p;
    const float pxf = pos_skip[(size_t)row * 3 + 0];
    const float pyf = pos_skip[(size_t)row * 3 + 1];
    const float pzf = pos_skip[(size_t)row * 3 + 2];

    uint32_t c0 = 0xFFFFFFFFu, c1 = 0xFFFFFFFFu, c2 = 0xFFFFFFFFu, c3 = 0xFFFFFFFFu;
    auto ins4u = [&](uint32_t k) {
      const bool l0 = k < c0, l1 = k < c1, l2 = k < c2, l3 = k < c3;
      const uint32_t n0 = l0 ? k  : c0;
      const uint32_t n1 = l0 ? c0 : (l1 ? k : c1);
      const uint32_t n2 = l1 ? c1 : (l2 ? k : c2);
      const uint32_t n3 = l2 ? c2 : (l3 ? k : c3);
      c0 = n0; c1 = n1; c2 = n2; c3 = n3;
    };
#pragma unroll 4
    for (int j = 0; j < 256; ++j) {
      const int i = j * 4 + sub;
      const float4 q = *(const float4*)&pc4[i * 4];
      const float dx = q.x - pxf;
      const float dy = q.y - pyf;
      const float dz = q.z - pzf;
      const float d = fmaf(dx, dx, fmaf(dy, dy, dz * dz));
      ins4u((__float_as_uint(d) & 0xFFFFFC00u) | (uint32_t)i);
    }
#pragma unroll
    for (int m = 1; m <= 2; m <<= 1) {
      const uint32_t e0 = (uint32_t)__shfl_xor((int)c0, m);
      const uint32_t e1 = (uint32_t)__shfl_xor((int)c1, m);
      const uint32_t e2 = (uint32_t)__shfl_xor((int)c2, m);
      const uint32_t e3 = (uint32_t)__shfl_xor((int)c3, m);
      ins4u(e0); ins4u(e1); ins4u(e2); ins4u(e3);
    }
    if (sub == 0) {
      const double pxd = (double)pxf, pyd = (double)pyf, pzd = (double)pzf;
      auto exd = [&](int i) -> double {
        const double dx = (double)pc4[i * 4 + 0] - pxd;
        const double dy = (double)pc4[i * 4 + 1] - pyd;
        const double dz = (double)pc4[i * 4 + 2] - pzd;
        return dx * dx + dy * dy + dz * dz;
      };
      const int j0 = (int)(c0 & 1023u), j1 = (int)(c1 & 1023u);
      const int j2 = (int)(c2 & 1023u), j3 = (int)(c3 & 1023u);
      double b0 = 1e300, b1 = 1e300, b2 = 1e300;
      int i0 = 0, i1 = 0, i2 = 0;
      ins3b(exd(j0), j0, b0, b1, b2, i0, i1, i2);
      ins3b(exd(j1), j1, b0, b1, b2, i0, i1, i2);
      ins3b(exd(j2), j2, b0, b1, b2, i0, i1, i2);
      ins3b(exd(j3), j3, b0, b1, b2, i0, i1, i2);
      const double w0 = 1.0 / (sqrt(b0) + 1e-8);
      const double w1 = 1.0 / (sqrt(b1) + 1e-8);
      const double w2 = 1.0 / (sqrt(b2) + 1e-8);
      const double den = w0 + w1 + w2 + 1e-8;
      idx_out[row] = make_int4(i0, i1, i2, 0);
      w_out[row] = make_float4((float)(w0 / den), (float)(w1 / den), (float)(w2 / den), 0.f);
    }
  } else if (blockIdx.x < 3072) {
    const int id = (blockIdx.x - 1024) * 256 + threadIdx.x;   // x: 2,097,152 f4
#pragma unroll
    for (int it = 0; it < 4; ++it) {
      const int i = id + it * 524288;
      const float4 v = *(const float4*)(x + (size_t)i * 4);
      ushort4 o = { f2bf(v.x), f2bf(v.y), f2bf(v.z), f2bf(v.w) };
      *(ushort4*)(xbf + (size_t)i * 4) = o;
    }
  } else if (blockIdx.x < 7168) {
    const int id = (blockIdx.x - 3072) * 256 + threadIdx.x;   // xs: 4,194,304 f4
#pragma unroll
    for (int it = 0; it < 4; ++it) {
      const int i = id + it * 1048576;
      const float4 v = *(const float4*)(xs + (size_t)i * 4);
      ushort4 o = { f2bf(v.x), f2bf(v.y), f2bf(v.z), f2bf(v.w) };
      *(ushort4*)(xsbf + (size_t)i * 4) = o;
    }
  } else {
    const int id = (blockIdx.x - 7168) * 256 + threadIdx.x;
    if (id < 262144) {                       // W1at[n][k] = W1[k][n], k<512
      const int n = id >> 9, k = id & 511;
      W1at[id] = f2bf(W1[(size_t)k * 512 + n]);
    } else if (id < 393216) {                // W1bt[n][k] = W1[512+k][n], k<256
      const int id2 = id - 262144;
      const int n = id2 >> 8, k = id2 & 255;
      W1bt[id2] = f2bf(W1[(size_t)(512 + k) * 512 + n]);
    } else if (id < 655360) {                // W2t[n][k] = W2[k][n]
      const int id3 = id - 393216;
      const int n = id3 >> 9, k = id3 & 511;
      W2t[id3] = f2bf(W2[(size_t)k * 512 + n]);
    }
  }
}

// ---------------------------------------------------------------------------
// 256x256 8-phase bf16 MFMA GEMM (T1..T5).
// COMBINE epilogue (S-GEMM): h2 = relu(acc + gather3(Y) + b1) -> bf16,
// eliminating the S round trip entirely. acc is the f32 x_skip@W1b partial.
// ---------------------------------------------------------------------------
template<int K, bool OUT_BF16, bool ACT, bool COMBINE>
__global__ __launch_bounds__(512, 2) void gemm_bias_relu(
    const ushort* __restrict__ A, const ushort* __restrict__ Bt,
    const float* __restrict__ bias, void* __restrict__ Cout, int M, int N,
    const ushort* __restrict__ Ybf, const int4* __restrict__ idx3,
    const float4* __restrict__ w3)
{
  constexpr int BM = 256, BN = 256, BK = 64, NT = K / BK;
  __shared__ ushort Asm[2][BM * BK];   // 2 x 32 KB
  __shared__ ushort Bsm[2][BN * BK];   // 2 x 32 KB
  const int tid  = threadIdx.x;
  const int lane = tid & 63;
  const int wave = tid >> 6;

  const int cpx  = gridDim.x >> 3;
  const int wgid = (blockIdx.x & 7) * cpx + (blockIdx.x >> 3);
  const int nbn  = N / BN;
  const int bm   = wgid / nbn;
  const int bn   = wgid - bm * nbn;
  const int row0 = bm * BM, col0 = bn * BN;
  const int wr = wave >> 2, wc = wave & 3;
  const int sbase = wave * 4096 + lane * 16;

  f32x4 acc[8][4] = {};

  auto stageA = [&](int buf, int kt) {
#pragma unroll
    for (int i = 0; i < 4; ++i) {
      const int o = sbase + i * 1024;
      const int r = o >> 7, s = (o & 127) >> 4;
      __builtin_amdgcn_global_load_lds(
          (const __attribute__((address_space(1))) void*)(A + (size_t)(row0 + r) * K + kt * BK + ((s ^ (r & 7)) << 3)),
          (__attribute__((address_space(3))) void*)((char*)&Asm[buf][0] + o), 16, 0, 0);
    }
  };
  auto stageB = [&](int buf, int kt) {
#pragma unroll
    for (int i = 0; i < 4; ++i) {
      const int o = sbase + i * 1024;
      const int r = o >> 7, s = (o & 127) >> 4;
      __builtin_amdgcn_global_load_lds(
          (const __attribute__((address_space(1))) void*)(Bt + (size_t)(col0 + r) * K + kt * BK + ((s ^ (r & 7)) << 3)),
          (__attribute__((address_space(3))) void*)((char*)&Bsm[buf][0] + o), 16, 0, 0);
    }
  };
  auto rdA = [&](int buf, int mi, int kk) -> short8 {
    const int ra = wr * 128 + mi * 16 + (lane & 15);
    const int s  = kk * 4 + (lane >> 4);
    return *(const short8*)((const char*)&Asm[buf][0] + ra * 128 + ((s ^ (ra & 7)) << 4));
  };
  auto rdB = [&](int buf, int ni, int kk) -> short8 {
    const int rb = wc * 64 + ni * 16 + (lane & 15);
    const int s  = kk * 4 + (lane >> 4);
    return *(const short8*)((const char*)&Bsm[buf][0] + rb * 128 + ((s ^ (rb & 7)) << 4));
  };

  stageA(0, 0); stageB(0, 0);
  asm volatile("s_waitcnt vmcnt(0)" ::: "memory");
  __builtin_amdgcn_s_barrier();

  int cur = 0;
#pragma unroll 1
  for (int t = 0; t < NT; ++t) {
    short8 av[4], bv[4];
    // phase 0: kk=0, mi 0..3 (+ stage A of t+1)
#pragma unroll
    for (int mi = 0; mi < 4; ++mi) av[mi] = rdA(cur, mi, 0);
#pragma unroll
    for (int ni = 0; ni < 4; ++ni) bv[ni] = rdB(cur, ni, 0);
    if (t + 1 < NT) stageA(cur ^ 1, t + 1);
    __builtin_amdgcn_s_barrier();
    asm volatile("s_waitcnt lgkmcnt(0)" ::: "memory");
    __builtin_amdgcn_sched_barrier(0);
    __builtin_amdgcn_s_setprio(1);
#pragma unroll
    for (int mi = 0; mi < 4; ++mi)
#pragma unroll
      for (int ni = 0; ni < 4; ++ni)
        acc[mi][ni] = __builtin_amdgcn_mfma_f32_16x16x32_bf16(av[mi], bv[ni], acc[mi][ni], 0, 0, 0);
    __builtin_amdgcn_s_setprio(0);
    __builtin_amdgcn_s_barrier();
    // phase 1: kk=0, mi 4..7 (+ stage B of t+1)
#pragma unroll
    for (int mi = 0; mi < 4; ++mi) av[mi] = rdA(cur, 4 + mi, 0);
    if (t + 1 < NT) stageB(cur ^ 1, t + 1);
    __builtin_amdgcn_s_barrier();
    asm volatile("s_waitcnt lgkmcnt(0)" ::: "memory");
    __builtin_amdgcn_sched_barrier(0);
    __builtin_amdgcn_s_setprio(1);
#pragma unroll
    for (int mi = 0; mi < 4; ++mi)
#pragma unroll
      for (int ni = 0; ni < 4; ++ni)
        acc[4 + mi][ni] = __builtin_amdgcn_mfma_f32_16x16x32_bf16(av[mi], bv[ni], acc[4 + mi][ni], 0, 0, 0);
    __builtin_amdgcn_s_setprio(0);
    __builtin_amdgcn_s_barrier();
    // phase 2: kk=1, mi 0..3
#pragma unroll
    for (int mi = 0; mi < 4; ++mi) av[mi] = rdA(cur, mi, 1);
#pragma unroll
    for (int ni = 0; ni < 4; ++ni) bv[ni] = rdB(cur, ni, 1);
    __builtin_amdgcn_s_barrier();
    asm volatile("s_waitcnt lgkmcnt(0)" ::: "memory");
    __builtin_amdgcn_sched_barrier(0);
    __builtin_amdgcn_s_setprio(1);
#pragma unroll
    for (int mi = 0; mi < 4; ++mi)
#pragma unroll
      for (int ni = 0; ni < 4; ++ni)
        acc[mi][ni] = __builtin_amdgcn_mfma_f32_16x16x32_bf16(av[mi], bv[ni], acc[mi][ni], 0, 0, 0);
    __builtin_amdgcn_s_setprio(0);
    __builtin_amdgcn_s_barrier();
    // phase 3: kk=1, mi 4..7 (+ vmcnt drain for t+1)
#pragma unroll
    for (int mi = 0; mi < 4; ++mi) av[mi] = rdA(cur, 4 + mi, 1);
    __builtin_amdgcn_s_barrier();
    asm volatile("s_waitcnt lgkmcnt(0)" ::: "memory");
    __builtin_amdgcn_sched_barrier(0);
    __builtin_amdgcn_s_setprio(1);
#pragma unroll
    for (int mi = 0; mi < 4; ++mi)
#pragma unroll
      for (int ni = 0; ni < 4; ++ni)
        acc[4 + mi][ni] = __builtin_amdgcn_mfma_f32_16x16x32_bf16(av[mi], bv[ni], acc[4 + mi][ni], 0, 0, 0);
    __builtin_amdgcn_s_setprio(0);
    asm volatile("s_waitcnt vmcnt(0)" ::: "memory");
    __builtin_amdgcn_s_barrier();
    cur ^= 1;
  }

  const int lc = lane & 15, lr = lane >> 4;
  if constexpr (COMBINE) {
    // h2[row][col] = relu(acc + w.x*Y[id.x][col] + w.y*Y[id.y][col]
    //                        + w.z*Y[id.z][col] + b1[col])
#pragma unroll
    for (int mi = 0; mi < 8; ++mi) {
#pragma unroll
      for (int r = 0; r < 4; ++r) {
        const int row = row0 + wr * 128 + mi * 16 + lr * 4 + r;
        const int4 id = idx3[row];
        const float4 w = w3[row];
        const ushort* Yb = Ybf + (size_t)(row >> 12) * 524288;
        const ushort* y0 = Yb + (size_t)id.x * 512;
        const ushort* y1 = Yb + (size_t)id.y * 512;
        const ushort* y2 = Yb + (size_t)id.z * 512;
#pragma unroll
        for (int ni = 0; ni < 4; ++ni) {
          const int col = col0 + wc * 64 + ni * 16 + lc;
          float v = acc[mi][ni][r]
                  + w.x * bf2f(y0[col])
                  + w.y * bf2f(y1[col])
                  + w.z * bf2f(y2[col])
                  + bias[col];
          v = v > 0.f ? v : 0.f;
          ((ushort*)Cout)[(size_t)row * 512 + col] = f2bf(v);
        }
      }
    }
  } else {
#pragma unroll
    for (int mi = 0; mi < 8; ++mi) {
#pragma unroll
      for (int ni = 0; ni < 4; ++ni) {
        const int col = col0 + wc * 64 + ni * 16 + lc;
        float bv2 = 0.f;
        if constexpr (ACT) bv2 = bias[col];
        const int rbase = row0 + wr * 128 + mi * 16 + lr * 4;
#pragma unroll
        for (int r = 0; r < 4; ++r) {
          float v = acc[mi][ni][r];
          if constexpr (ACT) { v += bv2; v = v > 0.f ? v : 0.f; }
          if (OUT_BF16) ((ushort*)Cout)[(size_t)(rbase + r) * N + col] = f2bf(v);
          else          ((float*)Cout)[(size_t)(rbase + r) * N + col] = v;
        }
      }
    }
  }
}

// ---------------------------------------------------------------------------
extern "C" void kernel_launch(void* const* d_in, const int* in_sizes, int n_in,
                              void* d_out, int out_size, void* d_ws, size_t ws_size,
                              hipStream_t stream) {
  const float* x        = (const float*)d_in[0];   // [16384, 512]
  const float* pos      = (const float*)d_in[1];   // [16384, 3]
  const float* x_skip   = (const float*)d_in[3];   // [65536, 256]
  const float* pos_skip = (const float*)d_in[4];   // [65536, 3]
  const float* W1       = (const float*)d_in[6];   // [768, 512]
  const float* b1       = (const float*)d_in[7];   // [512]
  const float* W2       = (const float*)d_in[8];   // [512, 512]
  const float* b2       = (const float*)d_in[9];   // [512]

  // d_out (134,217,728 B) as scratch — all consumed before GEMM2 overwrites:
  ushort* Ybf  = (ushort*)d_out;                        // [16384][512]  16.8 MB
  ushort* xbf  = (ushort*)((char*)d_out + 83886080);    // [16384][512]  16.8 MB
  ushort* xsbf = (ushort*)((char*)d_out + 100663296);   // [65536][256]  33.5 MB

  char* ws = (char*)d_ws;
  ushort* h2   = (ushort*)ws;                          // [65536][512] bf16, 67108864 B
  ushort* W1at = (ushort*)(ws + 67108864);             // [512][512] bf16, 524288 B
  ushort* W1bt = (ushort*)(ws + 67633152);             // [512][256] bf16, 262144 B
  ushort* W2t  = (ushort*)(ws + 67895296);             // [512][512] bf16, 524288 B
  int4*   idx3 = (int4*)  (ws + 68419584);             // [65536] int4, 1 MB
  float4* w3   = (float4*)(ws + 69468160);             // [65536] float4, 1 MB

  // KNN (blocks 0..1023) overlapped with all f32->bf16 converts
  prep_kernel<<<9728, 256, 0, stream>>>(pos, pos_skip, x, x_skip, W1, W2,
                                        idx3, w3, xbf, xsbf, W1at, W1bt, W2t);
  // Y = x @ W1[:512]  (coarse rows only: 16384 x 512, K=512)
  gemm_bias_relu<512, true, false, false><<<128, 512, 0, stream>>>(
      xbf, W1at, nullptr, (void*)Ybf, 16384, 512, nullptr, nullptr, nullptr);
  // h2 = relu(x_skip @ W1[512:768] + gather3(Y) + b1)   [S never materialized]
  gemm_bias_relu<256, true, false, true><<<512, 512, 0, stream>>>(
      xsbf, W1bt, b1, (void*)h2, 65536, 512, Ybf, idx3, w3);
  // out = relu(h2 @ W2 + b2), f32
  gemm_bias_relu<512, false, true, false><<<512, 512, 0, stream>>>(
      h2, W2t, b2, d_out, 65536, 512, nullptr, nullptr, nullptr);
}